// Round 1
// 2866.796 us; speedup vs baseline: 1.2216x; 1.2216x over previous
//
#include <hip/hip_runtime.h>

// Problem: N=32768 rows, Din=1024, HID=512, K=1024 codes, 3 codebooks.
// d_out layout (float32):
//   H @ 0 [32768,512] | codes @ 16777216 [32768,3] | key_idx @ 16875520 [32]
//   token_emb @ 16875552 [32768,1536] | L_vq @ 67207200 scalar
// ws layout (floats): z @ 0 (32768*1536; h1 overlaps head, dead before z),
//   en @ 50331648 (3*1024*512), rn @ 51904512 (98304), alpha @ 52002816 (32768),
//   fc1 @ 52035584 (1 int), flags1 @ 52035585 (2*12288 ints),
//   fc2 @ 52060161 (1 int), flags2 @ 52060162 (2*4096 ints),
//   en_hi @ 52068356 (3*1024*512 ushort), en_lo @ 52854788 (same)
//
// NUMERICS: reference computes dist = 2 - 2*sim in fp32 (bins of ulp(2)/2),
// argmin ties -> lowest code. Funnel:
//   tier 0: sim matrix on MFMA via bf16x3 split (hi*hi + lo*hi + hi*lo,
//           fp32 accum). Certified |dist_err| <= 2*3*2^-18 <= 2.4e-5.
//           Flag approx-gap < TAU_APPROX=1.25e-4 (covers wrong-winner 4eps
//           and rescue-needed TAU+2eps, ~30% margin).
//   tier 1: refine_fp32 rescans flagged (row,cb) over all 1024 codes in
//           exact fp32 from fp32 z -> reference-exact quantized argmin;
//           re-flags exact-gap < TAU_DIST=2e-5 for fp64 rescue.
//   tier 2: rescue_fp64 (unchanged): fp64 from h0 -> quantized truth.

#define BM 128
#define BN 128
#define BK 16
#define MAXF 4096          // fp64 rescue capacity
#define MAXF1 12288        // fp32 refine capacity
#define TAU_DIST 2e-5f     // exact-gap threshold -> fp64 rescue
#define TAU_APPROX 1.25e-4f // approx-gap threshold -> fp32 refine

#define CODES_OFF   16777216ULL
#define KEYIDX_OFF  16875520ULL
#define TOKEMB_OFF  16875552ULL
#define LVQ_OFF     67207200ULL

typedef __attribute__((ext_vector_type(8))) short short8;   // 8 bf16 (4 VGPR)
typedef __attribute__((ext_vector_type(4))) float f32x4;

#define MFMA_BF16(a, b, c) __builtin_amdgcn_mfma_f32_16x16x32_bf16(a, b, c, 0, 0, 0)

__device__ __forceinline__ unsigned flip_bits(float x) {
  unsigned b = __float_as_uint(x);
  return b ^ ((unsigned)((int)b >> 31) | 0x80000000u);
}
__device__ __forceinline__ float unflip_bits(unsigned ob) {
  unsigned b = (ob & 0x80000000u) ? (ob ^ 0x80000000u) : ~ob;
  return __uint_as_float(b);
}
// reference-exact dist: fl32(2 - 2*fl32(sim)); __f*_rn blocks fma contraction
__device__ __forceinline__ float qdist(float dot, float rnv) {
  float sim = __fmul_rn(dot, rnv);
  return __fadd_rn(2.0f, -__fmul_rn(2.0f, sim));
}
__device__ __forceinline__ float dist_of_key(unsigned long long q) {
  return unflip_bits(~(unsigned)(q >> 32));
}
// RNE bf16 two-term split: x = hi + lo + r, |r| <= 2^-18 |x|.
// x - hi is exact in fp32 (classic split), both roundings RNE.
__device__ __forceinline__ void split2(float x, unsigned& h, unsigned& l) {
  unsigned b = __float_as_uint(x);
  unsigned hb = (b + 0x7FFFu + ((b >> 16) & 1u)) & 0xFFFF0000u;
  h = hb >> 16;
  float r = x - __uint_as_float(hb);
  unsigned cbits = __float_as_uint(r);
  l = (cbits + 0x7FFFu + ((cbits >> 16) & 1u)) >> 16;
}

// ---------------------------------------------------------------------------
// C[m,n] = act(A @ B + bias). grid=(M/128,N/128), block 256, 8x8 microtile.
template<int RELU>
__global__ __launch_bounds__(256)
void gemm_f32(const float* __restrict__ A, int lda,
              const float* __restrict__ B, int ldb,
              const float* __restrict__ bias,
              float* __restrict__ C, int ldc, int K)
{
  __shared__ float As[BK][BM + 4];
  __shared__ float Bs[BK][BN + 4];
  const int tid = threadIdx.x;
  const int tx = tid & 15, ty = tid >> 4;
  const long m0 = (long)blockIdx.x * BM;
  const long n0 = (long)blockIdx.y * BN;

  float acc[8][8];
#pragma unroll
  for (int i = 0; i < 8; i++)
#pragma unroll
    for (int j = 0; j < 8; j++) acc[i][j] = 0.f;

  for (int k0 = 0; k0 < K; k0 += BK) {
#pragma unroll
    for (int i = 0; i < 2; i++) {
      int f4 = tid + i * 256;
      int row = f4 >> 2, kc = (f4 & 3) * 4;
      float4 v = *(const float4*)(A + (m0 + row) * lda + k0 + kc);
      As[kc + 0][row] = v.x; As[kc + 1][row] = v.y;
      As[kc + 2][row] = v.z; As[kc + 3][row] = v.w;
    }
#pragma unroll
    for (int i = 0; i < 2; i++) {
      int f4 = tid + i * 256;
      int kr = f4 >> 5, c4 = (f4 & 31) * 4;
      *(float4*)&Bs[kr][c4] = *(const float4*)(B + (long)(k0 + kr) * ldb + n0 + c4);
    }
    __syncthreads();
#pragma unroll
    for (int kk = 0; kk < BK; kk++) {
      float a[8], b[8];
      *(float4*)&a[0] = *(const float4*)&As[kk][ty * 8];
      *(float4*)&a[4] = *(const float4*)&As[kk][ty * 8 + 4];
      *(float4*)&b[0] = *(const float4*)&Bs[kk][tx * 4];
      *(float4*)&b[4] = *(const float4*)&Bs[kk][64 + tx * 4];
#pragma unroll
      for (int i = 0; i < 8; i++)
#pragma unroll
        for (int j = 0; j < 8; j++)
          acc[i][j] = fmaf(a[i], b[j], acc[i][j]);
    }
    __syncthreads();
  }

  float bv[8];
#pragma unroll
  for (int j = 0; j < 8; j++) {
    int col = (j < 4) ? (tx * 4 + j) : (64 + tx * 4 + (j - 4));
    bv[j] = bias[n0 + col];
  }
#pragma unroll
  for (int i = 0; i < 8; i++) {
    float o[8];
#pragma unroll
    for (int j = 0; j < 8; j++) {
      float v = acc[i][j] + bv[j];
      if (RELU) v = fmaxf(v, 0.f);
      o[j] = v;
    }
    float* cp = C + (m0 + ty * 8 + i) * (long)ldc + n0;
    *(float4*)(cp + tx * 4) = *(const float4*)&o[0];
    *(float4*)(cp + 64 + tx * 4) = *(const float4*)&o[4];
  }
}

// ---------------------------------------------------------------------------
// Tier 0: MFMA bf16x3 sim + argmin over quantized dist, tie -> lowest code.
// grid (256, 3), block 256 (4 waves, 2x2 wave grid, 64x64 per wave).
// z-tile split on the fly into LDS (hi/lo bf16, stride 40 elems = 80 B pad);
// en pre-split by cb_norm. Flags approx-near-ties into flags1 for refine.
__global__ __launch_bounds__(256)
void sim_argmax(const float* __restrict__ z,
                const float* __restrict__ en,
                const unsigned short* __restrict__ en_hi,
                const unsigned short* __restrict__ en_lo,
                const float* __restrict__ rn,
                float* __restrict__ out,
                float* __restrict__ lvq,
                int* __restrict__ fc1,
                int* __restrict__ flags1)
{
  __shared__ unsigned short Ah[128 * 40];
  __shared__ unsigned short Al[128 * 40];
  __shared__ unsigned short Bh[128 * 40];
  __shared__ unsigned short Bl[128 * 40];
  __shared__ unsigned long long redk[128][2];
  __shared__ float redd[128][2];
  __shared__ int bidx[128];
  __shared__ float dsum[128];

  const int tid = threadIdx.x;
  const int w = tid >> 6, wr = w >> 1, wc = w & 1;
  const int l = tid & 63, l15 = l & 15, lg = l >> 4;
  const int c = blockIdx.y;
  const long m0 = (long)blockIdx.x * BM;
  const float* Az = z + (long)c * 512;
  const float* Ben = en + (size_t)c * 524288;
  const size_t cb_base = (size_t)c * 524288;

  // 1/|z| for the 16 output rows this lane owns (D-layout: row=(l>>4)*4+r)
  float rrn[16];
#pragma unroll
  for (int fi = 0; fi < 4; fi++)
#pragma unroll
    for (int r = 0; r < 4; r++)
      rrn[fi * 4 + r] = rn[(long)c * 32768 + m0 + wr * 64 + fi * 16 + lg * 4 + r];

  unsigned long long best = 0ULL;   // key: (~flip(dist))<<32 | ~code
  float bestd2 = 1e30f;             // second-best dist so far

  for (int ct = 0; ct < 8; ct++) {
    const int n0 = ct * 128;
    f32x4 acc[4][4];
#pragma unroll
    for (int fi = 0; fi < 4; fi++)
#pragma unroll
      for (int fj = 0; fj < 4; fj++)
#pragma unroll
        for (int r = 0; r < 4; r++) acc[fi][fj][r] = 0.f;

    for (int k0 = 0; k0 < 512; k0 += 32) {
      // stage A: fp32 z tile [128][32] -> hi/lo bf16 LDS, RNE split
#pragma unroll
      for (int i = 0; i < 4; i++) {
        int f4 = tid + i * 256;
        int row = f4 >> 3, kc = (f4 & 7) * 4;
        float4 v = *(const float4*)(Az + (m0 + row) * 1536 + k0 + kc);
        unsigned hx, lx, hy, ly, hz, lz, hw, lw;
        split2(v.x, hx, lx); split2(v.y, hy, ly);
        split2(v.z, hz, lz); split2(v.w, hw, lw);
        uint2 hp, lp;
        hp.x = hx | (hy << 16); hp.y = hz | (hw << 16);
        lp.x = lx | (ly << 16); lp.y = lz | (lw << 16);
        *(uint2*)&Ah[row * 40 + kc] = hp;
        *(uint2*)&Al[row * 40 + kc] = lp;
      }
      // stage B: pre-split bf16 en tile [128 codes][32 k] (pure copy)
#pragma unroll
      for (int i = 0; i < 2; i++) {
        int q = tid + i * 256;
        int code = q >> 2, kc = (q & 3) * 8;
        size_t g = cb_base + (size_t)(n0 + code) * 512 + (k0 + kc);
        *(uint4*)&Bh[code * 40 + kc] = *(const uint4*)(en_hi + g);
        *(uint4*)&Bl[code * 40 + kc] = *(const uint4*)(en_lo + g);
      }
      __syncthreads();

      // fragments: A[i][k] i=l&15, k=(l>>4)*8+r ; B[k][j] j=l&15, same k
      short8 bh[4], bl[4];
#pragma unroll
      for (int f = 0; f < 4; f++) {
        int boff = (wc * 64 + f * 16 + l15) * 40 + lg * 8;
        bh[f] = *(const short8*)&Bh[boff];
        bl[f] = *(const short8*)&Bl[boff];
      }
#pragma unroll
      for (int fi = 0; fi < 4; fi++) {
        int aoff = (wr * 64 + fi * 16 + l15) * 40 + lg * 8;
        short8 ah = *(const short8*)&Ah[aoff];
        short8 al = *(const short8*)&Al[aoff];
#pragma unroll
        for (int fj = 0; fj < 4; fj++) {
          acc[fi][fj] = MFMA_BF16(ah, bh[fj], acc[fi][fj]);
          acc[fi][fj] = MFMA_BF16(al, bh[fj], acc[fi][fj]);
          acc[fi][fj] = MFMA_BF16(ah, bl[fj], acc[fi][fj]);
        }
      }
      __syncthreads();
    }

    // per-(fi,r): top-2 over this wave's 4 fj codes, then butterfly-merge
    // across the 16 lanes (l&15) that hold the same rows, disjoint codes.
#pragma unroll
    for (int fi = 0; fi < 4; fi++) {
      unsigned long long kk[4]; float dd[4];
#pragma unroll
      for (int r = 0; r < 4; r++) {
        float d1 = 1e30f, d2v = 1e30f; int bj = 0;
#pragma unroll
        for (int fj = 0; fj < 4; fj++) {
          float d = qdist(acc[fi][fj][r], rrn[fi * 4 + r]);
          if (d < d1) { d2v = d1; d1 = d; bj = fj; }   // fj asc => code asc
          else if (d < d2v) d2v = d;
        }
        int code = n0 + wc * 64 + bj * 16 + l15;
        kk[r] = ((unsigned long long)(~flip_bits(d1)) << 32) | (unsigned)(~code);
        dd[r] = d2v;
      }
#pragma unroll
      for (int m = 1; m < 16; m <<= 1) {
#pragma unroll
        for (int r = 0; r < 4; r++) {
          unsigned long long ok = __shfl_xor(kk[r], m, 64);
          float od = __shfl_xor(dd[r], m, 64);
          if (ok > kk[r]) { dd[r] = fminf(od, dist_of_key(kk[r])); kk[r] = ok; }
          else dd[r] = fminf(dd[r], dist_of_key(ok));
        }
      }
      if (l15 == 0) {
#pragma unroll
        for (int r = 0; r < 4; r++) {
          int row = wr * 64 + fi * 16 + lg * 4 + r;
          redk[row][wc] = kk[r];
          redd[row][wc] = dd[r];
        }
      }
    }
    __syncthreads();
    if (tid < 128) {
      unsigned long long kA = redk[tid][0]; float dA = redd[tid][0];
      unsigned long long kB = redk[tid][1]; float dB = redd[tid][1];
      unsigned long long km; float m2;
      if (kB > kA) { km = kB; m2 = fminf(dB, dist_of_key(kA)); }
      else         { km = kA; m2 = fminf(dA, dist_of_key(kB)); }
      if (km > best) {
        float oldd = (best == 0ULL) ? 1e30f : dist_of_key(best);
        bestd2 = fminf(oldd, m2);
        best = km;
      } else {
        bestd2 = fminf(bestd2, dist_of_key(km));
      }
    }
    __syncthreads();
  }

  if (tid < 128) {
    const long n = m0 + tid;
    const unsigned code = ~(unsigned)best;
    const float d1 = dist_of_key(best);
    out[CODES_OFF + (unsigned long long)n * 3 + c] = (float)code;
    bidx[tid] = (int)code;
    dsum[tid] = d1;                      // approx d1; lvq error ~1e-9, ok
    if (bestd2 - d1 < TAU_APPROX) {      // approx near-tie: fp32 refine
      int slot = atomicAdd(fc1, 1);
      if (slot < MAXF1) { flags1[2 * slot] = (int)n; flags1[2 * slot + 1] = c; }
    }
  }
  __syncthreads();
  if (tid < 64) dsum[tid] += dsum[tid + 64];
  __syncthreads();
  if (tid < 64) {
    float s = dsum[tid];
#pragma unroll
    for (int off = 32; off; off >>= 1) s += __shfl_xor(s, off);
    if (tid == 0) atomicAdd(lvq, s * (0.25f / (32768.f * 512.f)));
  }
  for (int t = tid; t < 128 * 128; t += 256) {
    int r = t >> 7, d4 = (t & 127) * 4;
    float4 v = *(const float4*)(Ben + (long)bidx[r] * 512 + d4);
    *(float4*)(out + TOKEMB_OFF + (unsigned long long)(m0 + r) * 1536 + c * 512 + d4) = v;
  }
}

// ---------------------------------------------------------------------------
// Tier 1: exact-fp32 rescan of flagged (row, cb) over all 1024 codes from
// the fp32 z row. Reference-exact quantized argmin, tie -> lowest code.
// Overwrites codes + token_emb; re-flags exact-gap < TAU_DIST for fp64 rescue.
__global__ __launch_bounds__(256)
void refine_fp32(const float* __restrict__ z,
                 const float* __restrict__ en,
                 const float* __restrict__ rn,
                 const int* __restrict__ fc1, const int* __restrict__ flags1,
                 int* __restrict__ fc2, int* __restrict__ flags2,
                 float* __restrict__ out)
{
  int nf = *fc1; if (nf > MAXF1) nf = MAXF1;
  const int b = blockIdx.x;
  if (b >= nf) return;
  const int n = flags1[2 * b];
  const int c = flags1[2 * b + 1];
  const int t = threadIdx.x;

  __shared__ float zs[512];
  __shared__ unsigned long long wk[4];
  __shared__ float wd2[4];
  __shared__ int fcode;

  zs[t]       = z[(size_t)n * 1536 + c * 512 + t];
  zs[t + 256] = z[(size_t)n * 1536 + c * 512 + 256 + t];
  const float rnv = rn[(size_t)c * 32768 + n];
  __syncthreads();

  const int wv = t >> 6, lane = t & 63;
  float zl[8];
#pragma unroll
  for (int m = 0; m < 8; m++) zl[m] = zs[lane * 8 + m];

  const float* cbase = en + (size_t)c * 524288;
  unsigned long long k1 = 0ULL; float d2 = 1e30f;
  for (int j = 0; j < 256; j++) {
    int k = (j << 2) | wv;                 // wave wv: k == wv (mod 4), asc
    const float* cr = cbase + (size_t)k * 512 + lane * 8;
    float4 c0 = *(const float4*)cr, c1 = *(const float4*)(cr + 4);
    float dt = zl[0] * c0.x + zl[1] * c0.y + zl[2] * c0.z + zl[3] * c0.w
             + zl[4] * c1.x + zl[5] * c1.y + zl[6] * c1.z + zl[7] * c1.w;
#pragma unroll
    for (int off = 32; off; off >>= 1) dt += __shfl_xor(dt, off);
    float d = qdist(dt, rnv);
    unsigned long long key =
        ((unsigned long long)(~flip_bits(d)) << 32) | (unsigned)(~k);
    if (key > k1) { d2 = fminf(d2, (k1 == 0ULL) ? 1e30f : dist_of_key(k1)); k1 = key; }
    else d2 = fminf(d2, d);
  }
  if (lane == 0) { wk[wv] = k1; wd2[wv] = d2; }
  __syncthreads();
  if (t == 0) {
    unsigned long long kb = wk[0]; float s2 = wd2[0];
#pragma unroll
    for (int w = 1; w < 4; w++) {
      unsigned long long q = wk[w]; float qd2 = wd2[w];
      if (q > kb) { s2 = fminf(qd2, dist_of_key(kb)); kb = q; }
      else s2 = fminf(s2, dist_of_key(q));
    }
    int code = (int)(~(unsigned)kb);
    float d1 = dist_of_key(kb);
    out[CODES_OFF + (unsigned long long)n * 3 + c] = (float)code;
    fcode = code;
    if (s2 - d1 < TAU_DIST) {            // exact near-tie: fp64 rescue
      int slot = atomicAdd(fc2, 1);
      if (slot < MAXF) { flags2[2 * slot] = n; flags2[2 * slot + 1] = c; }
    }
  }
  __syncthreads();
  const int fk = fcode;
  if (t < 128) {
    const float* er = en + ((size_t)c * 1024 + fk) * 512;
    float4 v = ((const float4*)er)[t];
    *(float4*)(out + TOKEMB_OFF + (unsigned long long)n * 1536 + c * 512 + t * 4) = v;
  }
}

// ---------------------------------------------------------------------------
// Tier 2: fp64 rescue — recompute flagged (row, codebook) from h0 in double,
// apply the reference's fp32 quantization, argmin with lowest-index tie-break.
__global__ __launch_bounds__(256)
void rescue_fp64(const float* __restrict__ h0,
                 const float* __restrict__ W1, const float* __restrict__ b1,
                 const float* __restrict__ W2, const float* __restrict__ b2,
                 const float* __restrict__ Wm, const float* __restrict__ bm,
                 const float* __restrict__ Wt, const float* __restrict__ bt,
                 const float* __restrict__ Wp, const float* __restrict__ bp,
                 const float* __restrict__ cbm, const float* __restrict__ cbt,
                 const float* __restrict__ cbp,
                 const float* __restrict__ en,
                 const int* __restrict__ flag_cnt, const int* __restrict__ flags,
                 float* __restrict__ out)
{
  int nf = *flag_cnt; if (nf > MAXF) nf = MAXF;
  const int b = blockIdx.x;
  if (b >= nf) return;
  const int n = flags[2 * b];
  const int c = flags[2 * b + 1];
  const int t = threadIdx.x;

  __shared__ double s1[512];
  __shared__ double s2[512];
  __shared__ double sred[256];
  __shared__ float sd4[4];
  __shared__ int sk4[4];
  __shared__ double shz;

  const float* Wc = (c == 0) ? Wm : (c == 1) ? Wt : Wp;
  const float* bc = (c == 0) ? bm : (c == 1) ? bt : bp;
  const float* cb = (c == 0) ? cbm : (c == 1) ? cbt : cbp;
  const float* h0r = h0 + (size_t)n * 1024;

  { // h1 = relu(h0 @ W1 + b1)
    double a0 = 0.0, a1 = 0.0;
    for (int i = 0; i < 1024; i++) {
      double h = (double)h0r[i];
      a0 = fma(h, (double)W1[(size_t)i * 512 + t], a0);
      a1 = fma(h, (double)W1[(size_t)i * 512 + t + 256], a1);
    }
    s1[t]       = fmax(a0 + (double)b1[t], 0.0);
    s1[t + 256] = fmax(a1 + (double)b1[t + 256], 0.0);
  }
  __syncthreads();
  { // H = relu(h1 @ W2 + b2)
    double a0 = 0.0, a1 = 0.0;
    for (int i = 0; i < 512; i++) {
      double h = s1[i];
      a0 = fma(h, (double)W2[(size_t)i * 512 + t], a0);
      a1 = fma(h, (double)W2[(size_t)i * 512 + t + 256], a1);
    }
    s2[t]       = fmax(a0 + (double)b2[t], 0.0);
    s2[t + 256] = fmax(a1 + (double)b2[t + 256], 0.0);
  }
  __syncthreads();
  { // z = H @ Wc + bc
    double a0 = 0.0, a1 = 0.0;
    for (int i = 0; i < 512; i++) {
      double h = s2[i];
      a0 = fma(h, (double)Wc[(size_t)i * 512 + t], a0);
      a1 = fma(h, (double)Wc[(size_t)i * 512 + t + 256], a1);
    }
    __syncthreads();
    s1[t]       = a0 + (double)bc[t];
    s1[t + 256] = a1 + (double)bc[t + 256];
  }
  __syncthreads();
  sred[t] = s1[t] * s1[t] + s1[t + 256] * s1[t + 256];
  __syncthreads();
  for (int s = 128; s > 0; s >>= 1) {
    if (t < s) sred[t] += sred[t + s];
    __syncthreads();
  }
  if (t == 0) shz = 1.0 / sqrt(sred[0] + 1e-12);
  __syncthreads();
  const double rz = shz;

  const int wv = t >> 6, lane = t & 63;
  double zl[8];
#pragma unroll
  for (int m = 0; m < 8; m++) zl[m] = s1[lane * 8 + m];
  float bd = 1e30f; int bkk = 1 << 30;
  for (int j = 0; j < 256; j++) {
    int k = (j << 2) | wv;
    const float* cr = cb + (size_t)k * 512 + lane * 8;
    float4 c0 = *(const float4*)cr, c1 = *(const float4*)(cr + 4);
    double x0 = c0.x, x1 = c0.y, x2 = c0.z, x3 = c0.w;
    double x4 = c1.x, x5 = c1.y, x6 = c1.z, x7 = c1.w;
    double dt = zl[0]*x0 + zl[1]*x1 + zl[2]*x2 + zl[3]*x3
              + zl[4]*x4 + zl[5]*x5 + zl[6]*x6 + zl[7]*x7;
    double nc = x0*x0 + x1*x1 + x2*x2 + x3*x3 + x4*x4 + x5*x5 + x6*x6 + x7*x7;
#pragma unroll
    for (int off = 32; off; off >>= 1) {
      dt += __shfl_xor(dt, off);
      nc += __shfl_xor(nc, off);
    }
    double sim64 = dt * rz * (1.0 / sqrt(nc + 1e-12));
    float s32 = (float)sim64;
    float d32 = __fadd_rn(2.0f, -__fmul_rn(2.0f, s32));
    if (d32 < bd) { bd = d32; bkk = k; }
  }
  if (lane == 0) { sd4[wv] = bd; sk4[wv] = bkk; }
  __syncthreads();
  if (t == 0) {
    float d = sd4[0]; int k = sk4[0];
#pragma unroll
    for (int w = 1; w < 4; w++)
      if (sd4[w] < d || (sd4[w] == d && sk4[w] < k)) { d = sd4[w]; k = sk4[w]; }
    sk4[0] = k;
    out[CODES_OFF + (unsigned long long)n * 3 + c] = (float)k;
  }
  __syncthreads();
  const int fk = sk4[0];
  if (t < 128) {
    const float* er = en + ((size_t)c * 1024 + fk) * 512;
    float4 v = ((const float4*)er)[t];
    *(float4*)(out + TOKEMB_OFF + (unsigned long long)n * 1536 + c * 512 + t * 4) = v;
  }
}

// ---------------------------------------------------------------------------
__global__ __launch_bounds__(256)
void row_rnorm(const float* __restrict__ z, float* __restrict__ rn)
{
  const int lane = threadIdx.x & 63;
  const long r = (long)blockIdx.x * 4 + (threadIdx.x >> 6);
  const int cc = (int)(r >> 15), n = (int)(r & 32767);
  const float* p = z + (long)n * 1536 + cc * 512 + lane * 8;
  float4 v0 = *(const float4*)p, v1 = *(const float4*)(p + 4);
  float s = v0.x * v0.x + v0.y * v0.y + v0.z * v0.z + v0.w * v0.w
          + v1.x * v1.x + v1.y * v1.y + v1.z * v1.z + v1.w * v1.w;
#pragma unroll
  for (int off = 32; off; off >>= 1) s += __shfl_xor(s, off);
  if (lane == 0) rn[r] = 1.f / sqrtf(s + 1e-12f);
}

// normalize codebooks -> en (fp32) and pre-split bf16 hi/lo for the MFMA sim
__global__ __launch_bounds__(256)
void cb_norm(const float* __restrict__ cbm, const float* __restrict__ cbt,
             const float* __restrict__ cbp, float* __restrict__ en,
             unsigned short* __restrict__ en_hi, unsigned short* __restrict__ en_lo)
{
  const int lane = threadIdx.x & 63;
  const long r = (long)blockIdx.x * 4 + (threadIdx.x >> 6);
  const int cc = (int)(r >> 10), k = (int)(r & 1023);
  const float* cb = (cc == 0) ? cbm : (cc == 1) ? cbt : cbp;
  const float* p = cb + (long)k * 512 + lane * 8;
  float4 v0 = *(const float4*)p, v1 = *(const float4*)(p + 4);
  float s = v0.x * v0.x + v0.y * v0.y + v0.z * v0.z + v0.w * v0.w
          + v1.x * v1.x + v1.y * v1.y + v1.z * v1.z + v1.w * v1.w;
#pragma unroll
  for (int off = 32; off; off >>= 1) s += __shfl_xor(s, off);
  float sc = 1.f / sqrtf(s + 1e-12f);
  v0.x *= sc; v0.y *= sc; v0.z *= sc; v0.w *= sc;
  v1.x *= sc; v1.y *= sc; v1.z *= sc; v1.w *= sc;
  const size_t g = (size_t)cc * 524288 + (size_t)k * 512 + lane * 8;
  float* q = en + g;
  *(float4*)q = v0; *(float4*)(q + 4) = v1;
  unsigned h[8], lo[8];
  split2(v0.x, h[0], lo[0]); split2(v0.y, h[1], lo[1]);
  split2(v0.z, h[2], lo[2]); split2(v0.w, h[3], lo[3]);
  split2(v1.x, h[4], lo[4]); split2(v1.y, h[5], lo[5]);
  split2(v1.z, h[6], lo[6]); split2(v1.w, h[7], lo[7]);
  uint4 hp, lp;
  hp.x = h[0] | (h[1] << 16);  hp.y = h[2] | (h[3] << 16);
  hp.z = h[4] | (h[5] << 16);  hp.w = h[6] | (h[7] << 16);
  lp.x = lo[0] | (lo[1] << 16); lp.y = lo[2] | (lo[3] << 16);
  lp.z = lo[4] | (lo[5] << 16); lp.w = lo[6] | (lo[7] << 16);
  *(uint4*)(en_hi + g) = hp;
  *(uint4*)(en_lo + g) = lp;
}

__global__ __launch_bounds__(256)
void logits_alpha(const float* __restrict__ H, const float* __restrict__ Wk,
                  const float* __restrict__ bk, float* __restrict__ alpha)
{
  const int lane = threadIdx.x & 63;
  const long n = (long)blockIdx.x * 4 + (threadIdx.x >> 6);
  const float* p = H + n * 512 + lane * 8;
  const float* w = Wk + lane * 8;
  float4 a0 = *(const float4*)p, a1 = *(const float4*)(p + 4);
  float4 w0 = *(const float4*)w, w1 = *(const float4*)(w + 4);
  float s = a0.x * w0.x + a0.y * w0.y + a0.z * w0.z + a0.w * w0.w
          + a1.x * w1.x + a1.y * w1.y + a1.z * w1.z + a1.w * w1.w;
#pragma unroll
  for (int off = 32; off; off >>= 1) s += __shfl_xor(s, off);
  if (lane == 0) alpha[n] = 1.f / (1.f + expf(-(s + bk[0])));
}

__global__ __launch_bounds__(1024)
void topk32(const float* __restrict__ alpha, float* __restrict__ out)
{
  __shared__ unsigned long long sk[1024];
  const int tid = threadIdx.x;
  unsigned long long prev = ~0ULL;
  for (int it = 0; it < 32; it++) {
    unsigned long long best = 0;
#pragma unroll 4
    for (int i = tid; i < 32768; i += 1024) {
      unsigned long long key =
          ((unsigned long long)flip_bits(alpha[i]) << 32) | (unsigned)(~i);
      if (key < prev && key > best) best = key;
    }
    sk[tid] = best;
    __syncthreads();
    for (int s = 512; s > 0; s >>= 1) {
      if (tid < s) { unsigned long long q = sk[tid + s]; if (q > sk[tid]) sk[tid] = q; }
      __syncthreads();
    }
    unsigned long long sel = sk[0];
    __syncthreads();
    if (tid == 0) out[it] = (float)(~(unsigned)sel);
    prev = sel;
  }
}

extern "C" void kernel_launch(void* const* d_in, const int* in_sizes, int n_in,
                              void* d_out, int out_size, void* d_ws, size_t ws_size,
                              hipStream_t stream)
{
  (void)in_sizes; (void)n_in; (void)out_size; (void)ws_size;
  const float* h0  = (const float*)d_in[0];
  const float* W1  = (const float*)d_in[1];
  const float* b1  = (const float*)d_in[2];
  const float* W2  = (const float*)d_in[3];
  const float* b2  = (const float*)d_in[4];
  const float* Wm  = (const float*)d_in[5];
  const float* bm  = (const float*)d_in[6];
  const float* Wt  = (const float*)d_in[7];
  const float* bt  = (const float*)d_in[8];
  const float* Wp  = (const float*)d_in[9];
  const float* bp  = (const float*)d_in[10];
  const float* cbm = (const float*)d_in[11];
  const float* cbt = (const float*)d_in[12];
  const float* cbp = (const float*)d_in[13];
  const float* Wk  = (const float*)d_in[14];
  const float* bk  = (const float*)d_in[15];
  float* out = (float*)d_out;
  float* ws  = (float*)d_ws;

  float* h1 = ws;                    // [32768,512], dead before z written
  float* z  = ws;                    // [32768,1536]
  float* en = ws + 50331648ULL;      // [3,1024,512]
  float* rn = ws + 51904512ULL;      // [3*32768]
  float* al = ws + 52002816ULL;      // [32768]
  int* fc1    = (int*)(ws + 52035584ULL);
  int* flags1 = (int*)(ws + 52035585ULL);            // [MAXF1][2]
  int* fc2    = (int*)(ws + 52060161ULL);
  int* flags2 = (int*)(ws + 52060162ULL);            // [MAXF][2]
  unsigned short* en_hi = (unsigned short*)(ws + 52068356ULL);  // [3*1024*512]
  unsigned short* en_lo = (unsigned short*)(ws + 52854788ULL);  // [3*1024*512]
  float* H  = out;
  float* lvq = out + LVQ_OFF;

  hipMemsetAsync(lvq, 0, sizeof(float), stream);
  hipMemsetAsync(fc1, 0, sizeof(int), stream);
  hipMemsetAsync(fc2, 0, sizeof(int), stream);

  gemm_f32<1><<<dim3(256, 4), 256, 0, stream>>>(h0, 1024, W1, 512, b1, h1, 512, 1024);
  gemm_f32<1><<<dim3(256, 4), 256, 0, stream>>>(h1, 512,  W2, 512, b2, H,  512, 512);
  gemm_f32<0><<<dim3(256, 4), 256, 0, stream>>>(H, 512, Wm, 512, bm, z + 0,    1536, 512);
  gemm_f32<0><<<dim3(256, 4), 256, 0, stream>>>(H, 512, Wt, 512, bt, z + 512,  1536, 512);
  gemm_f32<0><<<dim3(256, 4), 256, 0, stream>>>(H, 512, Wp, 512, bp, z + 1024, 1536, 512);

  row_rnorm<<<24576, 256, 0, stream>>>(z, rn);
  cb_norm<<<768, 256, 0, stream>>>(cbm, cbt, cbp, en, en_hi, en_lo);
  sim_argmax<<<dim3(256, 3), 256, 0, stream>>>(z, en, en_hi, en_lo, rn, out, lvq,
                                               fc1, flags1);
  refine_fp32<<<MAXF1, 256, 0, stream>>>(z, en, rn, fc1, flags1, fc2, flags2, out);
  rescue_fp64<<<MAXF, 256, 0, stream>>>(h0, W1, b1, W2, b2, Wm, bm, Wt, bt, Wp, bp,
                                        cbm, cbt, cbp, en, fc2, flags2, out);
  logits_alpha<<<8192, 256, 0, stream>>>(H, Wk, bk, al);
  topk32<<<1, 1024, 0, stream>>>(al, out + KEYIDX_OFF);
}

// Round 2
// 2493.634 us; speedup vs baseline: 1.4045x; 1.1496x over previous
//
#include <hip/hip_runtime.h>

// Problem: N=32768 rows, Din=1024, HID=512, K=1024 codes, 3 codebooks.
// d_out layout (float32):
//   H @ 0 [32768,512] | codes @ 16777216 [32768,3] | key_idx @ 16875520 [32]
//   token_emb @ 16875552 [32768,1536] | L_vq @ 67207200 scalar
// ws layout (floats):
//   zh plane @ 0 (ushort [32768][1536]) | zl plane @ 25165824 (ushort, same)
//     (h1 fp32 [32768,512] aliases the head; dead before z planes written)
//   en @ 50331648 (3*1024*512 f32), rn @ 51904512 (98304), alpha @ 52002816,
//   fc1 @ 52035584 (int), flags1 @ 52035585 (2*12288 ints),
//   fc2 @ 52060161 (int), flags2 @ 52060162 (2*4096 ints),
//   en_hi @ 52068356 (ushort 3*1024*512), en_lo @ 52854788 (same),
//   Wh @ 53641220 (ushort [3][512 n][512 k], transposed), Wl @ 54034436 (same)
//
// NUMERICS FUNNEL: reference computes dist = 2 - 2*sim in fp32 (bins of
// ulp(2)/2), argmin ties -> lowest code.
//   tier 0: z computed by bf16x3 MFMA GEMM (split H on the fly, pre-split W),
//           stored as bf16 hi/lo planes. sim matrix on MFMA from planes.
//           Ordering-relevant error: certified mfma-sim term <= 2.4e-5 plus
//           z~ statistical rounding noise (~1e-6 sigma, independent of
//           codebook). Flag approx-gap < TAU_APPROX = 1.25e-4.
//   tier 1: refine_fp32 recomputes z row EXACTLY in fp32 from H (out) and Wc,
//           recomputes rn, rescans all 1024 codes -> reference-exact
//           quantized argmin; re-flags exact-gap < TAU_DIST for fp64 rescue.
//   tier 2: rescue_fp64 (unchanged): fp64 from h0 -> quantized truth.

#define BM 128
#define BN 128
#define BK 16
#define MAXF 4096          // fp64 rescue capacity
#define MAXF1 12288        // fp32 refine capacity
#define TAU_DIST 2e-5f     // exact-gap threshold -> fp64 rescue
#define TAU_APPROX 1.25e-4f // approx-gap threshold -> fp32 refine

#define CODES_OFF   16777216ULL
#define KEYIDX_OFF  16875520ULL
#define TOKEMB_OFF  16875552ULL
#define LVQ_OFF     67207200ULL

typedef __attribute__((ext_vector_type(8))) short short8;   // 8 bf16 (4 VGPR)
typedef __attribute__((ext_vector_type(4))) float f32x4;

#define MFMA_BF16(a, b, c) __builtin_amdgcn_mfma_f32_16x16x32_bf16(a, b, c, 0, 0, 0)

__device__ __forceinline__ unsigned flip_bits(float x) {
  unsigned b = __float_as_uint(x);
  return b ^ ((unsigned)((int)b >> 31) | 0x80000000u);
}
__device__ __forceinline__ float unflip_bits(unsigned ob) {
  unsigned b = (ob & 0x80000000u) ? (ob ^ 0x80000000u) : ~ob;
  return __uint_as_float(b);
}
// reference-exact dist: fl32(2 - 2*fl32(sim)); __f*_rn blocks fma contraction
__device__ __forceinline__ float qdist(float dot, float rnv) {
  float sim = __fmul_rn(dot, rnv);
  return __fadd_rn(2.0f, -__fmul_rn(2.0f, sim));
}
__device__ __forceinline__ float dist_of_key(unsigned long long q) {
  return unflip_bits(~(unsigned)(q >> 32));
}
// RNE bf16 two-term split: x = hi + lo + r, |r| <= 2^-18 |x|.
__device__ __forceinline__ void split2(float x, unsigned& h, unsigned& l) {
  unsigned b = __float_as_uint(x);
  unsigned hb = (b + 0x7FFFu + ((b >> 16) & 1u)) & 0xFFFF0000u;
  h = hb >> 16;
  float r = x - __uint_as_float(hb);
  unsigned cbits = __float_as_uint(r);
  l = (cbits + 0x7FFFu + ((cbits >> 16) & 1u)) >> 16;
}

// ---------------------------------------------------------------------------
// C[m,n] = act(A @ B + bias). grid=(M/128,N/128), block 256, 8x8 microtile.
// Kept fp32-exact: produces h1 and H (H is a checked output and feeds topk).
template<int RELU>
__global__ __launch_bounds__(256)
void gemm_f32(const float* __restrict__ A, int lda,
              const float* __restrict__ B, int ldb,
              const float* __restrict__ bias,
              float* __restrict__ C, int ldc, int K)
{
  __shared__ float As[BK][BM + 4];
  __shared__ float Bs[BK][BN + 4];
  const int tid = threadIdx.x;
  const int tx = tid & 15, ty = tid >> 4;
  const long m0 = (long)blockIdx.x * BM;
  const long n0 = (long)blockIdx.y * BN;

  float acc[8][8];
#pragma unroll
  for (int i = 0; i < 8; i++)
#pragma unroll
    for (int j = 0; j < 8; j++) acc[i][j] = 0.f;

  for (int k0 = 0; k0 < K; k0 += BK) {
#pragma unroll
    for (int i = 0; i < 2; i++) {
      int f4 = tid + i * 256;
      int row = f4 >> 2, kc = (f4 & 3) * 4;
      float4 v = *(const float4*)(A + (m0 + row) * lda + k0 + kc);
      As[kc + 0][row] = v.x; As[kc + 1][row] = v.y;
      As[kc + 2][row] = v.z; As[kc + 3][row] = v.w;
    }
#pragma unroll
    for (int i = 0; i < 2; i++) {
      int f4 = tid + i * 256;
      int kr = f4 >> 5, c4 = (f4 & 31) * 4;
      *(float4*)&Bs[kr][c4] = *(const float4*)(B + (long)(k0 + kr) * ldb + n0 + c4);
    }
    __syncthreads();
#pragma unroll
    for (int kk = 0; kk < BK; kk++) {
      float a[8], b[8];
      *(float4*)&a[0] = *(const float4*)&As[kk][ty * 8];
      *(float4*)&a[4] = *(const float4*)&As[kk][ty * 8 + 4];
      *(float4*)&b[0] = *(const float4*)&Bs[kk][tx * 4];
      *(float4*)&b[4] = *(const float4*)&Bs[kk][64 + tx * 4];
#pragma unroll
      for (int i = 0; i < 8; i++)
#pragma unroll
        for (int j = 0; j < 8; j++)
          acc[i][j] = fmaf(a[i], b[j], acc[i][j]);
    }
    __syncthreads();
  }

  float bv[8];
#pragma unroll
  for (int j = 0; j < 8; j++) {
    int col = (j < 4) ? (tx * 4 + j) : (64 + tx * 4 + (j - 4));
    bv[j] = bias[n0 + col];
  }
#pragma unroll
  for (int i = 0; i < 8; i++) {
    float o[8];
#pragma unroll
    for (int j = 0; j < 8; j++) {
      float v = acc[i][j] + bv[j];
      if (RELU) v = fmaxf(v, 0.f);
      o[j] = v;
    }
    float* cp = C + (m0 + ty * 8 + i) * (long)ldc + n0;
    *(float4*)(cp + tx * 4) = *(const float4*)&o[0];
    *(float4*)(cp + 64 + tx * 4) = *(const float4*)&o[4];
  }
}

// ---------------------------------------------------------------------------
// Split + transpose W{m,t,p} -> bf16 hi/lo planes [c][n][k] (k contiguous).
// One thread per (c, n, k-group-of-8). Tiny (3 MB source, L2-resident).
__global__ __launch_bounds__(256)
void w_split(const float* __restrict__ Wm, const float* __restrict__ Wt,
             const float* __restrict__ Wp,
             unsigned short* __restrict__ wh, unsigned short* __restrict__ wl)
{
  int t = blockIdx.x * 256 + threadIdx.x;      // 3*512*64 = 98304 threads
  int c = t >> 15, rem = t & 32767;
  int n = rem >> 6, kg = (rem & 63) * 8;
  const float* W = (c == 0) ? Wm : (c == 1) ? Wt : Wp;
  unsigned h[8], l[8];
#pragma unroll
  for (int i = 0; i < 8; i++) {
    float v = W[(size_t)(kg + i) * 512 + n];   // W is [k][n]
    split2(v, h[i], l[i]);
  }
  uint4 hp, lp;
  hp.x = h[0] | (h[1] << 16); hp.y = h[2] | (h[3] << 16);
  hp.z = h[4] | (h[5] << 16); hp.w = h[6] | (h[7] << 16);
  lp.x = l[0] | (l[1] << 16); lp.y = l[2] | (l[3] << 16);
  lp.z = l[4] | (l[5] << 16); lp.w = l[6] | (l[7] << 16);
  size_t g = ((size_t)c * 512 + n) * 512 + kg;
  *(uint4*)(wh + g) = hp;
  *(uint4*)(wl + g) = lp;
}

// ---------------------------------------------------------------------------
// z = H @ Wc + bc via bf16x3 MFMA, written directly as hi/lo bf16 planes.
// grid (256 m-tiles, 3 codebooks), 512 threads = 8 waves (2 row x 4 col),
// per-wave tile 64x128, full N=512 per block (no cross-tile A re-split).
__global__ __launch_bounds__(512, 2)
void z_mfma(const float* __restrict__ H,
            const unsigned short* __restrict__ wh,
            const unsigned short* __restrict__ wl,
            const float* __restrict__ bm, const float* __restrict__ bt,
            const float* __restrict__ bp,
            unsigned short* __restrict__ zh, unsigned short* __restrict__ zl)
{
  __shared__ unsigned short Ah[128 * 40];
  __shared__ unsigned short Al[128 * 40];
  __shared__ unsigned short Bh[512 * 40];
  __shared__ unsigned short Bl[512 * 40];

  const int tid = threadIdx.x;
  const int w = tid >> 6, wr = w >> 2, wc = w & 3;
  const int l = tid & 63, l15 = l & 15, lg = l >> 4;
  const int c = blockIdx.y;
  const long m0 = (long)blockIdx.x * BM;
  const size_t wbase = (size_t)c * 512 * 512;

  f32x4 acc[4][8];
#pragma unroll
  for (int fi = 0; fi < 4; fi++)
#pragma unroll
    for (int fj = 0; fj < 8; fj++)
#pragma unroll
      for (int r = 0; r < 4; r++) acc[fi][fj][r] = 0.f;

  for (int k0 = 0; k0 < 512; k0 += 32) {
    // stage A: fp32 H tile [128][32] -> hi/lo bf16 LDS (split on the fly)
#pragma unroll
    for (int i = 0; i < 2; i++) {
      int f4 = tid + i * 512;
      int row = f4 >> 3, kc = (f4 & 7) * 4;
      float4 v = *(const float4*)(H + (m0 + row) * 512 + k0 + kc);
      unsigned hx, lx, hy, ly, hz, lz, hw, lw;
      split2(v.x, hx, lx); split2(v.y, hy, ly);
      split2(v.z, hz, lz); split2(v.w, hw, lw);
      uint2 hp, lp;
      hp.x = hx | (hy << 16); hp.y = hz | (hw << 16);
      lp.x = lx | (ly << 16); lp.y = lz | (lw << 16);
      *(uint2*)&Ah[row * 40 + kc] = hp;
      *(uint2*)&Al[row * 40 + kc] = lp;
    }
    // stage B: pre-split W planes [512 n][32 k] (pure copy)
#pragma unroll
    for (int j = 0; j < 4; j++) {
      int q = tid + j * 512;
      int n = q >> 2, kg = (q & 3) * 8;
      size_t g = wbase + (size_t)n * 512 + k0 + kg;
      *(uint4*)&Bh[n * 40 + kg] = *(const uint4*)(wh + g);
      *(uint4*)&Bl[n * 40 + kg] = *(const uint4*)(wl + g);
    }
    __syncthreads();

    short8 bh[8], bl[8];
#pragma unroll
    for (int fj = 0; fj < 8; fj++) {
      int boff = (wc * 128 + fj * 16 + l15) * 40 + lg * 8;
      bh[fj] = *(const short8*)&Bh[boff];
      bl[fj] = *(const short8*)&Bl[boff];
    }
#pragma unroll
    for (int fi = 0; fi < 4; fi++) {
      int aoff = (wr * 64 + fi * 16 + l15) * 40 + lg * 8;
      short8 ah = *(const short8*)&Ah[aoff];
      short8 al = *(const short8*)&Al[aoff];
#pragma unroll
      for (int fj = 0; fj < 8; fj++) {
        acc[fi][fj] = MFMA_BF16(ah, bh[fj], acc[fi][fj]);
        acc[fi][fj] = MFMA_BF16(al, bh[fj], acc[fi][fj]);
        acc[fi][fj] = MFMA_BF16(ah, bl[fj], acc[fi][fj]);
      }
    }
    __syncthreads();
  }

  const float* bc = (c == 0) ? bm : (c == 1) ? bt : bp;
  float bcv[8];
#pragma unroll
  for (int fj = 0; fj < 8; fj++) bcv[fj] = bc[wc * 128 + fj * 16 + l15];
#pragma unroll
  for (int fi = 0; fi < 4; fi++) {
#pragma unroll
    for (int fj = 0; fj < 8; fj++) {
      int col = wc * 128 + fj * 16 + l15;
#pragma unroll
      for (int r = 0; r < 4; r++) {
        long row = m0 + wr * 64 + fi * 16 + lg * 4 + r;
        float v = acc[fi][fj][r] + bcv[fj];
        unsigned h, lo;
        split2(v, h, lo);
        size_t g = (size_t)row * 1536 + (size_t)c * 512 + col;
        zh[g] = (unsigned short)h;
        zl[g] = (unsigned short)lo;
      }
    }
  }
}

// ---------------------------------------------------------------------------
// Tier 0: MFMA bf16x3 sim + argmin over quantized dist, tie -> lowest code.
// grid (256, 3), block 256 (4 waves, 2x2 wave grid, 64x64 per wave).
// A-staging is now a pure uint4 copy from the pre-split z planes.
__global__ __launch_bounds__(256)
void sim_argmax(const unsigned short* __restrict__ zh,
                const unsigned short* __restrict__ zl,
                const float* __restrict__ en,
                const unsigned short* __restrict__ en_hi,
                const unsigned short* __restrict__ en_lo,
                const float* __restrict__ rn,
                float* __restrict__ out,
                float* __restrict__ lvq,
                int* __restrict__ fc1,
                int* __restrict__ flags1)
{
  __shared__ unsigned short Ah[128 * 40];
  __shared__ unsigned short Al[128 * 40];
  __shared__ unsigned short Bh[128 * 40];
  __shared__ unsigned short Bl[128 * 40];
  __shared__ unsigned long long redk[128][2];
  __shared__ float redd[128][2];
  __shared__ int bidx[128];
  __shared__ float dsum[128];

  const int tid = threadIdx.x;
  const int w = tid >> 6, wr = w >> 1, wc = w & 1;
  const int l = tid & 63, l15 = l & 15, lg = l >> 4;
  const int c = blockIdx.y;
  const long m0 = (long)blockIdx.x * BM;
  const float* Ben = en + (size_t)c * 524288;
  const size_t cb_base = (size_t)c * 524288;

  float rrn[16];
#pragma unroll
  for (int fi = 0; fi < 4; fi++)
#pragma unroll
    for (int r = 0; r < 4; r++)
      rrn[fi * 4 + r] = rn[(long)c * 32768 + m0 + wr * 64 + fi * 16 + lg * 4 + r];

  unsigned long long best = 0ULL;   // key: (~flip(dist))<<32 | ~code
  float bestd2 = 1e30f;             // second-best dist so far

  for (int ct = 0; ct < 8; ct++) {
    const int n0 = ct * 128;
    f32x4 acc[4][4];
#pragma unroll
    for (int fi = 0; fi < 4; fi++)
#pragma unroll
      for (int fj = 0; fj < 4; fj++)
#pragma unroll
        for (int r = 0; r < 4; r++) acc[fi][fj][r] = 0.f;

    for (int k0 = 0; k0 < 512; k0 += 32) {
      // stage A: copy pre-split z planes [128][32] (no VALU split)
#pragma unroll
      for (int i = 0; i < 2; i++) {
        int q = tid + i * 256;
        int row = q >> 2, kc = (q & 3) * 8;
        size_t g = (size_t)(m0 + row) * 1536 + (size_t)c * 512 + k0 + kc;
        *(uint4*)&Ah[row * 40 + kc] = *(const uint4*)(zh + g);
        *(uint4*)&Al[row * 40 + kc] = *(const uint4*)(zl + g);
      }
      // stage B: pre-split bf16 en tile [128 codes][32 k] (pure copy)
#pragma unroll
      for (int i = 0; i < 2; i++) {
        int q = tid + i * 256;
        int code = q >> 2, kc = (q & 3) * 8;
        size_t g = cb_base + (size_t)(n0 + code) * 512 + (k0 + kc);
        *(uint4*)&Bh[code * 40 + kc] = *(const uint4*)(en_hi + g);
        *(uint4*)&Bl[code * 40 + kc] = *(const uint4*)(en_lo + g);
      }
      __syncthreads();

      short8 bh[4], bl[4];
#pragma unroll
      for (int f = 0; f < 4; f++) {
        int boff = (wc * 64 + f * 16 + l15) * 40 + lg * 8;
        bh[f] = *(const short8*)&Bh[boff];
        bl[f] = *(const short8*)&Bl[boff];
      }
#pragma unroll
      for (int fi = 0; fi < 4; fi++) {
        int aoff = (wr * 64 + fi * 16 + l15) * 40 + lg * 8;
        short8 ah = *(const short8*)&Ah[aoff];
        short8 al = *(const short8*)&Al[aoff];
#pragma unroll
        for (int fj = 0; fj < 4; fj++) {
          acc[fi][fj] = MFMA_BF16(ah, bh[fj], acc[fi][fj]);
          acc[fi][fj] = MFMA_BF16(al, bh[fj], acc[fi][fj]);
          acc[fi][fj] = MFMA_BF16(ah, bl[fj], acc[fi][fj]);
        }
      }
      __syncthreads();
    }

    // per-(fi,r): top-2 over this wave's 4 fj codes, butterfly-merge over l15
#pragma unroll
    for (int fi = 0; fi < 4; fi++) {
      unsigned long long kk[4]; float dd[4];
#pragma unroll
      for (int r = 0; r < 4; r++) {
        float d1 = 1e30f, d2v = 1e30f; int bj = 0;
#pragma unroll
        for (int fj = 0; fj < 4; fj++) {
          float d = qdist(acc[fi][fj][r], rrn[fi * 4 + r]);
          if (d < d1) { d2v = d1; d1 = d; bj = fj; }   // fj asc => code asc
          else if (d < d2v) d2v = d;
        }
        int code = n0 + wc * 64 + bj * 16 + l15;
        kk[r] = ((unsigned long long)(~flip_bits(d1)) << 32) | (unsigned)(~code);
        dd[r] = d2v;
      }
#pragma unroll
      for (int m = 1; m < 16; m <<= 1) {
#pragma unroll
        for (int r = 0; r < 4; r++) {
          unsigned long long ok = __shfl_xor(kk[r], m, 64);
          float od = __shfl_xor(dd[r], m, 64);
          if (ok > kk[r]) { dd[r] = fminf(od, dist_of_key(kk[r])); kk[r] = ok; }
          else dd[r] = fminf(dd[r], dist_of_key(ok));
        }
      }
      if (l15 == 0) {
#pragma unroll
        for (int r = 0; r < 4; r++) {
          int row = wr * 64 + fi * 16 + lg * 4 + r;
          redk[row][wc] = kk[r];
          redd[row][wc] = dd[r];
        }
      }
    }
    __syncthreads();
    if (tid < 128) {
      unsigned long long kA = redk[tid][0]; float dA = redd[tid][0];
      unsigned long long kB = redk[tid][1]; float dB = redd[tid][1];
      unsigned long long km; float m2;
      if (kB > kA) { km = kB; m2 = fminf(dB, dist_of_key(kA)); }
      else         { km = kA; m2 = fminf(dA, dist_of_key(kB)); }
      if (km > best) {
        float oldd = (best == 0ULL) ? 1e30f : dist_of_key(best);
        bestd2 = fminf(oldd, m2);
        best = km;
      } else {
        bestd2 = fminf(bestd2, dist_of_key(km));
      }
    }
    __syncthreads();
  }

  if (tid < 128) {
    const long n = m0 + tid;
    const unsigned code = ~(unsigned)best;
    const float d1 = dist_of_key(best);
    out[CODES_OFF + (unsigned long long)n * 3 + c] = (float)code;
    bidx[tid] = (int)code;
    dsum[tid] = d1;                      // approx d1; lvq error negligible
    if (bestd2 - d1 < TAU_APPROX) {      // approx near-tie: fp32 refine
      int slot = atomicAdd(fc1, 1);
      if (slot < MAXF1) { flags1[2 * slot] = (int)n; flags1[2 * slot + 1] = c; }
    }
  }
  __syncthreads();
  if (tid < 64) dsum[tid] += dsum[tid + 64];
  __syncthreads();
  if (tid < 64) {
    float s = dsum[tid];
#pragma unroll
    for (int off = 32; off; off >>= 1) s += __shfl_xor(s, off);
    if (tid == 0) atomicAdd(lvq, s * (0.25f / (32768.f * 512.f)));
  }
  for (int t = tid; t < 128 * 128; t += 256) {
    int r = t >> 7, d4 = (t & 127) * 4;
    float4 v = *(const float4*)(Ben + (long)bidx[r] * 512 + d4);
    *(float4*)(out + TOKEMB_OFF + (unsigned long long)(m0 + r) * 1536 + c * 512 + d4) = v;
  }
}

// ---------------------------------------------------------------------------
// Tier 1: recompute z row EXACTLY in fp32 from H (out) and Wc, recompute rn,
// rescan all 1024 codes. Reference-exact quantized argmin, tie -> lowest.
// Overwrites codes + token_emb; re-flags exact-gap < TAU_DIST for fp64 rescue.
__global__ __launch_bounds__(256)
void refine_fp32(const float* __restrict__ H,
                 const float* __restrict__ Wm, const float* __restrict__ bm,
                 const float* __restrict__ Wt, const float* __restrict__ bt,
                 const float* __restrict__ Wp, const float* __restrict__ bp,
                 const float* __restrict__ en,
                 const int* __restrict__ fc1, const int* __restrict__ flags1,
                 int* __restrict__ fc2, int* __restrict__ flags2,
                 float* __restrict__ out)
{
  int nf = *fc1; if (nf > MAXF1) nf = MAXF1;
  const int b = blockIdx.x;
  if (b >= nf) return;
  const int n = flags1[2 * b];
  const int c = flags1[2 * b + 1];
  const int t = threadIdx.x;

  __shared__ float sH[512];
  __shared__ float zs[512];
  __shared__ float sred[256];
  __shared__ unsigned long long wk[4];
  __shared__ float wd2[4];
  __shared__ int fcode;
  __shared__ float srn;

  const float* Wc = (c == 0) ? Wm : (c == 1) ? Wt : Wp;
  const float* bc = (c == 0) ? bm : (c == 1) ? bt : bp;

  sH[t]       = H[(size_t)n * 512 + t];
  sH[t + 256] = H[(size_t)n * 512 + 256 + t];
  __syncthreads();

  { // z = H @ Wc + bc (exact fp32, sequential k chain per output)
    float a0 = 0.f, a1 = 0.f;
    for (int i = 0; i < 512; i++) {
      float h = sH[i];
      a0 = fmaf(h, Wc[(size_t)i * 512 + t], a0);
      a1 = fmaf(h, Wc[(size_t)i * 512 + t + 256], a1);
    }
    float z0 = a0 + bc[t];
    float z1 = a1 + bc[t + 256];
    zs[t] = z0; zs[t + 256] = z1;
    sred[t] = z0 * z0 + z1 * z1;
  }
  __syncthreads();
  for (int s = 128; s > 0; s >>= 1) {
    if (t < s) sred[t] += sred[t + s];
    __syncthreads();
  }
  if (t == 0) srn = 1.f / sqrtf(sred[0] + 1e-12f);
  __syncthreads();
  const float rnv = srn;

  const int wv = t >> 6, lane = t & 63;
  float zlv[8];
#pragma unroll
  for (int m = 0; m < 8; m++) zlv[m] = zs[lane * 8 + m];

  const float* cbase = en + (size_t)c * 524288;
  unsigned long long k1 = 0ULL; float d2 = 1e30f;
  for (int j = 0; j < 256; j++) {
    int k = (j << 2) | wv;                 // wave wv: k == wv (mod 4), asc
    const float* cr = cbase + (size_t)k * 512 + lane * 8;
    float4 c0 = *(const float4*)cr, c1 = *(const float4*)(cr + 4);
    float dt = zlv[0] * c0.x + zlv[1] * c0.y + zlv[2] * c0.z + zlv[3] * c0.w
             + zlv[4] * c1.x + zlv[5] * c1.y + zlv[6] * c1.z + zlv[7] * c1.w;
#pragma unroll
    for (int off = 32; off; off >>= 1) dt += __shfl_xor(dt, off);
    float d = qdist(dt, rnv);
    unsigned long long key =
        ((unsigned long long)(~flip_bits(d)) << 32) | (unsigned)(~k);
    if (key > k1) { d2 = fminf(d2, (k1 == 0ULL) ? 1e30f : dist_of_key(k1)); k1 = key; }
    else d2 = fminf(d2, d);
  }
  if (lane == 0) { wk[wv] = k1; wd2[wv] = d2; }
  __syncthreads();
  if (t == 0) {
    unsigned long long kb = wk[0]; float s2 = wd2[0];
#pragma unroll
    for (int w = 1; w < 4; w++) {
      unsigned long long q = wk[w]; float qd2 = wd2[w];
      if (q > kb) { s2 = fminf(qd2, dist_of_key(kb)); kb = q; }
      else s2 = fminf(s2, dist_of_key(q));
    }
    int code = (int)(~(unsigned)kb);
    float d1 = dist_of_key(kb);
    out[CODES_OFF + (unsigned long long)n * 3 + c] = (float)code;
    fcode = code;
    if (s2 - d1 < TAU_DIST) {            // exact near-tie: fp64 rescue
      int slot = atomicAdd(fc2, 1);
      if (slot < MAXF) { flags2[2 * slot] = n; flags2[2 * slot + 1] = c; }
    }
  }
  __syncthreads();
  const int fk = fcode;
  if (t < 128) {
    const float* er = en + ((size_t)c * 1024 + fk) * 512;
    float4 v = ((const float4*)er)[t];
    *(float4*)(out + TOKEMB_OFF + (unsigned long long)n * 1536 + c * 512 + t * 4) = v;
  }
}

// ---------------------------------------------------------------------------
// Tier 2: fp64 rescue — recompute flagged (row, codebook) from h0 in double,
// apply the reference's fp32 quantization, argmin with lowest-index tie-break.
__global__ __launch_bounds__(256)
void rescue_fp64(const float* __restrict__ h0,
                 const float* __restrict__ W1, const float* __restrict__ b1,
                 const float* __restrict__ W2, const float* __restrict__ b2,
                 const float* __restrict__ Wm, const float* __restrict__ bm,
                 const float* __restrict__ Wt, const float* __restrict__ bt,
                 const float* __restrict__ Wp, const float* __restrict__ bp,
                 const float* __restrict__ cbm, const float* __restrict__ cbt,
                 const float* __restrict__ cbp,
                 const float* __restrict__ en,
                 const int* __restrict__ flag_cnt, const int* __restrict__ flags,
                 float* __restrict__ out)
{
  int nf = *flag_cnt; if (nf > MAXF) nf = MAXF;
  const int b = blockIdx.x;
  if (b >= nf) return;
  const int n = flags[2 * b];
  const int c = flags[2 * b + 1];
  const int t = threadIdx.x;

  __shared__ double s1[512];
  __shared__ double s2[512];
  __shared__ double sred[256];
  __shared__ float sd4[4];
  __shared__ int sk4[4];
  __shared__ double shz;

  const float* Wc = (c == 0) ? Wm : (c == 1) ? Wt : Wp;
  const float* bc = (c == 0) ? bm : (c == 1) ? bt : bp;
  const float* cb = (c == 0) ? cbm : (c == 1) ? cbt : cbp;
  const float* h0r = h0 + (size_t)n * 1024;

  { // h1 = relu(h0 @ W1 + b1)
    double a0 = 0.0, a1 = 0.0;
    for (int i = 0; i < 1024; i++) {
      double h = (double)h0r[i];
      a0 = fma(h, (double)W1[(size_t)i * 512 + t], a0);
      a1 = fma(h, (double)W1[(size_t)i * 512 + t + 256], a1);
    }
    s1[t]       = fmax(a0 + (double)b1[t], 0.0);
    s1[t + 256] = fmax(a1 + (double)b1[t + 256], 0.0);
  }
  __syncthreads();
  { // H = relu(h1 @ W2 + b2)
    double a0 = 0.0, a1 = 0.0;
    for (int i = 0; i < 512; i++) {
      double h = s1[i];
      a0 = fma(h, (double)W2[(size_t)i * 512 + t], a0);
      a1 = fma(h, (double)W2[(size_t)i * 512 + t + 256], a1);
    }
    s2[t]       = fmax(a0 + (double)b2[t], 0.0);
    s2[t + 256] = fmax(a1 + (double)b2[t + 256], 0.0);
  }
  __syncthreads();
  { // z = H @ Wc + bc
    double a0 = 0.0, a1 = 0.0;
    for (int i = 0; i < 512; i++) {
      double h = s2[i];
      a0 = fma(h, (double)Wc[(size_t)i * 512 + t], a0);
      a1 = fma(h, (double)Wc[(size_t)i * 512 + t + 256], a1);
    }
    __syncthreads();
    s1[t]       = a0 + (double)bc[t];
    s1[t + 256] = a1 + (double)bc[t + 256];
  }
  __syncthreads();
  sred[t] = s1[t] * s1[t] + s1[t + 256] * s1[t + 256];
  __syncthreads();
  for (int s = 128; s > 0; s >>= 1) {
    if (t < s) sred[t] += sred[t + s];
    __syncthreads();
  }
  if (t == 0) shz = 1.0 / sqrt(sred[0] + 1e-12);
  __syncthreads();
  const double rz = shz;

  const int wv = t >> 6, lane = t & 63;
  double zl[8];
#pragma unroll
  for (int m = 0; m < 8; m++) zl[m] = s1[lane * 8 + m];
  float bd = 1e30f; int bkk = 1 << 30;
  for (int j = 0; j < 256; j++) {
    int k = (j << 2) | wv;
    const float* cr = cb + (size_t)k * 512 + lane * 8;
    float4 c0 = *(const float4*)cr, c1 = *(const float4*)(cr + 4);
    double x0 = c0.x, x1 = c0.y, x2 = c0.z, x3 = c0.w;
    double x4 = c1.x, x5 = c1.y, x6 = c1.z, x7 = c1.w;
    double dt = zl[0]*x0 + zl[1]*x1 + zl[2]*x2 + zl[3]*x3
              + zl[4]*x4 + zl[5]*x5 + zl[6]*x6 + zl[7]*x7;
    double nc = x0*x0 + x1*x1 + x2*x2 + x3*x3 + x4*x4 + x5*x5 + x6*x6 + x7*x7;
#pragma unroll
    for (int off = 32; off; off >>= 1) {
      dt += __shfl_xor(dt, off);
      nc += __shfl_xor(nc, off);
    }
    double sim64 = dt * rz * (1.0 / sqrt(nc + 1e-12));
    float s32 = (float)sim64;
    float d32 = __fadd_rn(2.0f, -__fmul_rn(2.0f, s32));
    if (d32 < bd) { bd = d32; bkk = k; }
  }
  if (lane == 0) { sd4[wv] = bd; sk4[wv] = bkk; }
  __syncthreads();
  if (t == 0) {
    float d = sd4[0]; int k = sk4[0];
#pragma unroll
    for (int w = 1; w < 4; w++)
      if (sd4[w] < d || (sd4[w] == d && sk4[w] < k)) { d = sd4[w]; k = sk4[w]; }
    sk4[0] = k;
    out[CODES_OFF + (unsigned long long)n * 3 + c] = (float)k;
  }
  __syncthreads();
  const int fk = sk4[0];
  if (t < 128) {
    const float* er = en + ((size_t)c * 1024 + fk) * 512;
    float4 v = ((const float4*)er)[t];
    *(float4*)(out + TOKEMB_OFF + (unsigned long long)n * 1536 + c * 512 + t * 4) = v;
  }
}

// ---------------------------------------------------------------------------
// rn = 1/||z~|| from the hi/lo planes (z~ = hi + lo reconstructed).
__global__ __launch_bounds__(256)
void row_rnorm(const unsigned short* __restrict__ zh,
               const unsigned short* __restrict__ zl,
               float* __restrict__ rn)
{
  const int lane = threadIdx.x & 63;
  const long r = (long)blockIdx.x * 4 + (threadIdx.x >> 6);
  const int cc = (int)(r >> 15), n = (int)(r & 32767);
  const size_t base = (size_t)n * 1536 + (size_t)cc * 512 + lane * 8;
  uint4 h = *(const uint4*)(zh + base);
  uint4 lo = *(const uint4*)(zl + base);
  float s = 0.f;
  const unsigned hw[4] = {h.x, h.y, h.z, h.w};
  const unsigned lw[4] = {lo.x, lo.y, lo.z, lo.w};
#pragma unroll
  for (int i = 0; i < 4; i++) {
    float ze = __uint_as_float(hw[i] << 16) + __uint_as_float(lw[i] << 16);
    float zo = __uint_as_float(hw[i] & 0xFFFF0000u) + __uint_as_float(lw[i] & 0xFFFF0000u);
    s = fmaf(ze, ze, s);
    s = fmaf(zo, zo, s);
  }
#pragma unroll
  for (int off = 32; off; off >>= 1) s += __shfl_xor(s, off);
  if (lane == 0) rn[r] = 1.f / sqrtf(s + 1e-12f);
}

// normalize codebooks -> en (fp32) and pre-split bf16 hi/lo for the MFMA sim
__global__ __launch_bounds__(256)
void cb_norm(const float* __restrict__ cbm, const float* __restrict__ cbt,
             const float* __restrict__ cbp, float* __restrict__ en,
             unsigned short* __restrict__ en_hi, unsigned short* __restrict__ en_lo)
{
  const int lane = threadIdx.x & 63;
  const long r = (long)blockIdx.x * 4 + (threadIdx.x >> 6);
  const int cc = (int)(r >> 10), k = (int)(r & 1023);
  const float* cb = (cc == 0) ? cbm : (cc == 1) ? cbt : cbp;
  const float* p = cb + (long)k * 512 + lane * 8;
  float4 v0 = *(const float4*)p, v1 = *(const float4*)(p + 4);
  float s = v0.x * v0.x + v0.y * v0.y + v0.z * v0.z + v0.w * v0.w
          + v1.x * v1.x + v1.y * v1.y + v1.z * v1.z + v1.w * v1.w;
#pragma unroll
  for (int off = 32; off; off >>= 1) s += __shfl_xor(s, off);
  float sc = 1.f / sqrtf(s + 1e-12f);
  v0.x *= sc; v0.y *= sc; v0.z *= sc; v0.w *= sc;
  v1.x *= sc; v1.y *= sc; v1.z *= sc; v1.w *= sc;
  const size_t g = (size_t)cc * 524288 + (size_t)k * 512 + lane * 8;
  float* q = en + g;
  *(float4*)q = v0; *(float4*)(q + 4) = v1;
  unsigned h[8], lo[8];
  split2(v0.x, h[0], lo[0]); split2(v0.y, h[1], lo[1]);
  split2(v0.z, h[2], lo[2]); split2(v0.w, h[3], lo[3]);
  split2(v1.x, h[4], lo[4]); split2(v1.y, h[5], lo[5]);
  split2(v1.z, h[6], lo[6]); split2(v1.w, h[7], lo[7]);
  uint4 hp, lp;
  hp.x = h[0] | (h[1] << 16);  hp.y = h[2] | (h[3] << 16);
  hp.z = h[4] | (h[5] << 16);  hp.w = h[6] | (h[7] << 16);
  lp.x = lo[0] | (lo[1] << 16); lp.y = lo[2] | (lo[3] << 16);
  lp.z = lo[4] | (lo[5] << 16); lp.w = lo[6] | (lo[7] << 16);
  *(uint4*)(en_hi + g) = hp;
  *(uint4*)(en_lo + g) = lp;
}

__global__ __launch_bounds__(256)
void logits_alpha(const float* __restrict__ H, const float* __restrict__ Wk,
                  const float* __restrict__ bk, float* __restrict__ alpha)
{
  const int lane = threadIdx.x & 63;
  const long n = (long)blockIdx.x * 4 + (threadIdx.x >> 6);
  const float* p = H + n * 512 + lane * 8;
  const float* w = Wk + lane * 8;
  float4 a0 = *(const float4*)p, a1 = *(const float4*)(p + 4);
  float4 w0 = *(const float4*)w, w1 = *(const float4*)(w + 4);
  float s = a0.x * w0.x + a0.y * w0.y + a0.z * w0.z + a0.w * w0.w
          + a1.x * w1.x + a1.y * w1.y + a1.z * w1.z + a1.w * w1.w;
#pragma unroll
  for (int off = 32; off; off >>= 1) s += __shfl_xor(s, off);
  if (lane == 0) alpha[n] = 1.f / (1.f + expf(-(s + bk[0])));
}

__global__ __launch_bounds__(1024)
void topk32(const float* __restrict__ alpha, float* __restrict__ out)
{
  __shared__ unsigned long long sk[1024];
  const int tid = threadIdx.x;
  unsigned long long prev = ~0ULL;
  for (int it = 0; it < 32; it++) {
    unsigned long long best = 0;
#pragma unroll 4
    for (int i = tid; i < 32768; i += 1024) {
      unsigned long long key =
          ((unsigned long long)flip_bits(alpha[i]) << 32) | (unsigned)(~i);
      if (key < prev && key > best) best = key;
    }
    sk[tid] = best;
    __syncthreads();
    for (int s = 512; s > 0; s >>= 1) {
      if (tid < s) { unsigned long long q = sk[tid + s]; if (q > sk[tid]) sk[tid] = q; }
      __syncthreads();
    }
    unsigned long long sel = sk[0];
    __syncthreads();
    if (tid == 0) out[it] = (float)(~(unsigned)sel);
    prev = sel;
  }
}

extern "C" void kernel_launch(void* const* d_in, const int* in_sizes, int n_in,
                              void* d_out, int out_size, void* d_ws, size_t ws_size,
                              hipStream_t stream)
{
  (void)in_sizes; (void)n_in; (void)out_size; (void)ws_size;
  const float* h0  = (const float*)d_in[0];
  const float* W1  = (const float*)d_in[1];
  const float* b1  = (const float*)d_in[2];
  const float* W2  = (const float*)d_in[3];
  const float* b2  = (const float*)d_in[4];
  const float* Wm  = (const float*)d_in[5];
  const float* bm  = (const float*)d_in[6];
  const float* Wt  = (const float*)d_in[7];
  const float* bt  = (const float*)d_in[8];
  const float* Wp  = (const float*)d_in[9];
  const float* bp  = (const float*)d_in[10];
  const float* cbm = (const float*)d_in[11];
  const float* cbt = (const float*)d_in[12];
  const float* cbp = (const float*)d_in[13];
  const float* Wk  = (const float*)d_in[14];
  const float* bk  = (const float*)d_in[15];
  float* out = (float*)d_out;
  float* ws  = (float*)d_ws;

  float* h1 = ws;                    // [32768,512] fp32, dead before z planes
  unsigned short* zh = (unsigned short*)ws;                 // [32768][1536]
  unsigned short* zl = (unsigned short*)ws + 50331648ULL;   // [32768][1536]
  float* en = ws + 50331648ULL;      // [3,1024,512] fp32
  float* rn = ws + 51904512ULL;      // [3*32768]
  float* al = ws + 52002816ULL;      // [32768]
  int* fc1    = (int*)(ws + 52035584ULL);
  int* flags1 = (int*)(ws + 52035585ULL);            // [MAXF1][2]
  int* fc2    = (int*)(ws + 52060161ULL);
  int* flags2 = (int*)(ws + 52060162ULL);            // [MAXF][2]
  unsigned short* en_hi = (unsigned short*)(ws + 52068356ULL);  // [3*1024*512]
  unsigned short* en_lo = (unsigned short*)(ws + 52854788ULL);  // [3*1024*512]
  unsigned short* Wh = (unsigned short*)(ws + 53641220ULL);     // [3][512][512]
  unsigned short* Wl = (unsigned short*)(ws + 54034436ULL);     // [3][512][512]
  float* H  = out;
  float* lvq = out + LVQ_OFF;

  hipMemsetAsync(lvq, 0, sizeof(float), stream);
  hipMemsetAsync(fc1, 0, sizeof(int), stream);
  hipMemsetAsync(fc2, 0, sizeof(int), stream);

  gemm_f32<1><<<dim3(256, 4), 256, 0, stream>>>(h0, 1024, W1, 512, b1, h1, 512, 1024);
  gemm_f32<1><<<dim3(256, 4), 256, 0, stream>>>(h1, 512,  W2, 512, b2, H,  512, 512);

  w_split<<<384, 256, 0, stream>>>(Wm, Wt, Wp, Wh, Wl);
  z_mfma<<<dim3(256, 3), 512, 0, stream>>>(H, Wh, Wl, bm, bt, bp, zh, zl);

  row_rnorm<<<24576, 256, 0, stream>>>(zh, zl, rn);
  cb_norm<<<768, 256, 0, stream>>>(cbm, cbt, cbp, en, en_hi, en_lo);
  sim_argmax<<<dim3(256, 3), 256, 0, stream>>>(zh, zl, en, en_hi, en_lo, rn, out, lvq,
                                               fc1, flags1);
  refine_fp32<<<MAXF1, 256, 0, stream>>>(H, Wm, bm, Wt, bt, Wp, bp, en,
                                         fc1, flags1, fc2, flags2, out);
  rescue_fp64<<<MAXF, 256, 0, stream>>>(h0, W1, b1, W2, b2, Wm, bm, Wt, bt, Wp, bp,
                                        cbm, cbt, cbp, en, fc2, flags2, out);
  logits_alpha<<<8192, 256, 0, stream>>>(H, Wk, bk, al);
  topk32<<<1, 1024, 0, stream>>>(al, out + KEYIDX_OFF);
}

// Round 3
// 2304.226 us; speedup vs baseline: 1.5199x; 1.0822x over previous
//
#include <hip/hip_runtime.h>

// Problem: N=32768 rows, Din=1024, HID=512, K=1024 codes, 3 codebooks.
// d_out layout (float32):
//   H @ 0 [32768,512] | codes @ 16777216 [32768,3] | key_idx @ 16875520 [32]
//   token_emb @ 16875552 [32768,1536] | L_vq @ 67207200 scalar
// ws layout (bytes):
//   [0, 96MB)    zh plane (ushort [32768][1536])    -- late phase
//   [96, 192MB)  zl plane                            -- late phase
//     early phase overlays (dead before Z kernels write planes):
//       h1 fp32 [32768,512] @ 0 (64MB)
//       W1h @ 64MB (1MB) | W1l @ 65MB | W2h @ 66MB (0.5MB) | W2l @ 66.5MB
//   en @ float-ofs 50331648 (3*1024*512 f32), rn @ 51904512 (98304),
//   alpha @ 52002816, fc1 @ 52035584, flags1 @ 52035585 (2*12288),
//   fc2 @ 52060161, flags2 @ 52060162 (2*4096),
//   en_hi @ 52068356 (ushort 3*1024*512), en_lo @ 52854788,
//   Wh @ 53641220 (ushort [3][512][512] transposed), Wl @ 54034436
//
// NUMERICS FUNNEL: reference computes dist = 2 - 2*sim in fp32 (bins of
// ulp(2)/2), argmin ties -> lowest code.
//   tier 0: ALL gemms on MFMA via bf16x3 split (hi*hi + lo*hi + hi*lo, fp32
//           accum; per-GEMM statistical error ~1e-6 rel == same class as
//           fp32 accumulation-order noise vs jax). z stored as bf16 hi/lo
//           planes. sim matrix on MFMA; certified mfma-sim term <= 2.4e-5.
//           Flag approx-gap < TAU_APPROX = 1.25e-4.
//   tier 1: refine_fp32 recomputes z row EXACTLY in fp32 from our H (out),
//           recomputes rn, rescans all 1024 codes -> reference-exact
//           quantized argmin; re-flags exact-gap < TAU_DIST for fp64 rescue.
//   tier 2: rescue_fp64: fp64 from h0 (reference truth) -> quantized truth.

#define BM 128
#define MAXF 4096          // fp64 rescue capacity
#define MAXF1 12288        // fp32 refine capacity
#define TAU_DIST 2e-5f     // exact-gap threshold -> fp64 rescue
#define TAU_APPROX 1.25e-4f // approx-gap threshold -> fp32 refine

#define CODES_OFF   16777216ULL
#define KEYIDX_OFF  16875520ULL
#define TOKEMB_OFF  16875552ULL
#define LVQ_OFF     67207200ULL

typedef __attribute__((ext_vector_type(8))) short short8;   // 8 bf16 (4 VGPR)
typedef __attribute__((ext_vector_type(4))) float f32x4;

#define MFMA_BF16(a, b, c) __builtin_amdgcn_mfma_f32_16x16x32_bf16(a, b, c, 0, 0, 0)

__device__ __forceinline__ unsigned flip_bits(float x) {
  unsigned b = __float_as_uint(x);
  return b ^ ((unsigned)((int)b >> 31) | 0x80000000u);
}
__device__ __forceinline__ float unflip_bits(unsigned ob) {
  unsigned b = (ob & 0x80000000u) ? (ob ^ 0x80000000u) : ~ob;
  return __uint_as_float(b);
}
// reference-exact dist: fl32(2 - 2*fl32(sim)); __f*_rn blocks fma contraction
__device__ __forceinline__ float qdist(float dot, float rnv) {
  float sim = __fmul_rn(dot, rnv);
  return __fadd_rn(2.0f, -__fmul_rn(2.0f, sim));
}
__device__ __forceinline__ float dist_of_key(unsigned long long q) {
  return unflip_bits(~(unsigned)(q >> 32));
}
// RNE bf16 two-term split: x = hi + lo + r, |r| <= 2^-18 |x|.
__device__ __forceinline__ void split2(float x, unsigned& h, unsigned& l) {
  unsigned b = __float_as_uint(x);
  unsigned hb = (b + 0x7FFFu + ((b >> 16) & 1u)) & 0xFFFF0000u;
  h = hb >> 16;
  float r = x - __uint_as_float(hb);
  unsigned cbits = __float_as_uint(r);
  l = (cbits + 0x7FFFu + ((cbits >> 16) & 1u)) >> 16;
}

// ---------------------------------------------------------------------------
// Split + transpose a [K][512] fp32 weight matrix -> bf16 hi/lo planes
// [512 n][K k] (k contiguous). grid = K/4 blocks of 256.
__global__ __launch_bounds__(256)
void wsplit_g(const float* __restrict__ W,
              unsigned short* __restrict__ wh, unsigned short* __restrict__ wl,
              int K)
{
  int t = blockIdx.x * 256 + threadIdx.x;      // 512*(K/8) threads
  int kg8 = K >> 3;
  int n = t / kg8, kg = (t % kg8) * 8;
  unsigned h[8], l[8];
#pragma unroll
  for (int i = 0; i < 8; i++) {
    float v = W[(size_t)(kg + i) * 512 + n];   // W is [k][n]
    split2(v, h[i], l[i]);
  }
  uint4 hp, lp;
  hp.x = h[0] | (h[1] << 16); hp.y = h[2] | (h[3] << 16);
  hp.z = h[4] | (h[5] << 16); hp.w = h[6] | (h[7] << 16);
  lp.x = l[0] | (l[1] << 16); lp.y = l[2] | (l[3] << 16);
  lp.z = l[4] | (l[5] << 16); lp.w = l[6] | (l[7] << 16);
  size_t g = (size_t)n * K + kg;
  *(uint4*)(wh + g) = hp;
  *(uint4*)(wl + g) = lp;
}

// ---------------------------------------------------------------------------
// Unified bf16x3 MFMA GEMM: C[m,n] = act(A @ Wc^T + bias), A fp32 [M][K]
// (split hi/lo on the fly into LDS), W pre-split planes [512 n][K k].
// grid = 256 m-tiles, 512 threads = 8 waves (2 row x 4 col), wave tile
// 64x128, full N=512 per block.
// OUTPLANES=0: write fp32 C (dword stores, 16-lane/64B segments).
// OUTPLANES=1: write bf16 hi/lo planes, LDS-staged for coalesced uint4.
template<int RELU, int OUTPLANES>
__global__ __launch_bounds__(512, 2)
void mfma_gemm(const float* __restrict__ A, int lda, int K,
               const unsigned short* __restrict__ wh,
               const unsigned short* __restrict__ wl,
               const float* __restrict__ bias,
               float* __restrict__ Cf, int ldc,
               unsigned short* __restrict__ zh, unsigned short* __restrict__ zl,
               int ldz, int colOff)
{
  __shared__ __align__(16) unsigned char smem[102400];
  unsigned short* Ah = (unsigned short*)smem;          // [128][40]
  unsigned short* Al = Ah + 5120;
  unsigned short* Bh = Al + 5120;                      // [512][40]
  unsigned short* Bl = Bh + 20480;

  const int tid = threadIdx.x;
  const int w = tid >> 6, wr = w >> 2, wc = w & 3;
  const int l = tid & 63, l15 = l & 15, lg = l >> 4;
  const long m0 = (long)blockIdx.x * BM;

  f32x4 acc[4][8];
#pragma unroll
  for (int fi = 0; fi < 4; fi++)
#pragma unroll
    for (int fj = 0; fj < 8; fj++)
#pragma unroll
      for (int r = 0; r < 4; r++) acc[fi][fj][r] = 0.f;

  for (int k0 = 0; k0 < K; k0 += 32) {
    // stage A: fp32 tile [128][32] -> hi/lo bf16 LDS (split on the fly)
#pragma unroll
    for (int i = 0; i < 2; i++) {
      int f4 = tid + i * 512;
      int row = f4 >> 3, kc = (f4 & 7) * 4;
      float4 v = *(const float4*)(A + (m0 + row) * lda + k0 + kc);
      unsigned hx, lx, hy, ly, hz, lz, hw, lw;
      split2(v.x, hx, lx); split2(v.y, hy, ly);
      split2(v.z, hz, lz); split2(v.w, hw, lw);
      uint2 hp, lp;
      hp.x = hx | (hy << 16); hp.y = hz | (hw << 16);
      lp.x = lx | (ly << 16); lp.y = lz | (lw << 16);
      *(uint2*)&Ah[row * 40 + kc] = hp;
      *(uint2*)&Al[row * 40 + kc] = lp;
    }
    // stage B: pre-split W planes [512 n][32 k] (pure copy)
#pragma unroll
    for (int j = 0; j < 4; j++) {
      int q = tid + j * 512;
      int n = q >> 2, kg = (q & 3) * 8;
      size_t g = (size_t)n * K + k0 + kg;
      *(uint4*)&Bh[n * 40 + kg] = *(const uint4*)(wh + g);
      *(uint4*)&Bl[n * 40 + kg] = *(const uint4*)(wl + g);
    }
    __syncthreads();

    short8 bh[8], bl[8];
#pragma unroll
    for (int fj = 0; fj < 8; fj++) {
      int boff = (wc * 128 + fj * 16 + l15) * 40 + lg * 8;
      bh[fj] = *(const short8*)&Bh[boff];
      bl[fj] = *(const short8*)&Bl[boff];
    }
#pragma unroll
    for (int fi = 0; fi < 4; fi++) {
      int aoff = (wr * 64 + fi * 16 + l15) * 40 + lg * 8;
      short8 ah = *(const short8*)&Ah[aoff];
      short8 al = *(const short8*)&Al[aoff];
#pragma unroll
      for (int fj = 0; fj < 8; fj++) {
        acc[fi][fj] = MFMA_BF16(ah, bh[fj], acc[fi][fj]);
        acc[fi][fj] = MFMA_BF16(al, bh[fj], acc[fi][fj]);
        acc[fi][fj] = MFMA_BF16(ah, bl[fj], acc[fi][fj]);
      }
    }
    __syncthreads();
  }

  float bcv[8];
#pragma unroll
  for (int fj = 0; fj < 8; fj++) bcv[fj] = bias[wc * 128 + fj * 16 + l15];

  if (OUTPLANES == 0) {
    // direct fp32 stores: 16 consecutive lanes cover 16 consecutive cols
#pragma unroll
    for (int fi = 0; fi < 4; fi++)
#pragma unroll
      for (int fj = 0; fj < 8; fj++) {
        int col = wc * 128 + fj * 16 + l15;
#pragma unroll
        for (int r = 0; r < 4; r++) {
          long row = m0 + wr * 64 + fi * 16 + lg * 4 + r;
          float v = acc[fi][fj][r] + bcv[fj];
          if (RELU) v = fmaxf(v, 0.f);
          Cf[row * (long)ldc + col] = v;
        }
      }
  } else {
    // LDS-staged plane writes: 4 phases (2 row-halves x {hi,lo})
    unsigned short* ep = (unsigned short*)smem;        // [64][512]
#pragma unroll
    for (int half = 0; half < 2; half++) {
#pragma unroll
      for (int pl = 0; pl < 2; pl++) {
        if (wr == half) {
#pragma unroll
          for (int fi = 0; fi < 4; fi++)
#pragma unroll
            for (int fj = 0; fj < 8; fj++) {
              int col = wc * 128 + fj * 16 + l15;
#pragma unroll
              for (int r = 0; r < 4; r++) {
                int row = fi * 16 + lg * 4 + r;       // 0..63
                float v = acc[fi][fj][r] + bcv[fj];
                unsigned h, lo;
                split2(v, h, lo);
                ep[row * 512 + col] = (unsigned short)(pl ? lo : h);
              }
            }
        }
        __syncthreads();
        unsigned short* dst = pl ? zl : zh;
        for (int u = tid; u < 4096; u += 512) {
          int row = u >> 6, c8 = (u & 63) * 8;
          size_t g = (size_t)(m0 + half * 64 + row) * ldz + colOff + c8;
          *(uint4*)(dst + g) = *(const uint4*)(ep + row * 512 + c8);
        }
        __syncthreads();
      }
    }
  }
}

// ---------------------------------------------------------------------------
// Tier 0: MFMA bf16x3 sim + argmin over quantized dist, tie -> lowest code.
// grid (256, 3), block 256 (4 waves, 2x2 wave grid, 64x64 per wave).
__global__ __launch_bounds__(256)
void sim_argmax(const unsigned short* __restrict__ zh,
                const unsigned short* __restrict__ zl,
                const float* __restrict__ en,
                const unsigned short* __restrict__ en_hi,
                const unsigned short* __restrict__ en_lo,
                const float* __restrict__ rn,
                float* __restrict__ out,
                float* __restrict__ lvq,
                int* __restrict__ fc1,
                int* __restrict__ flags1)
{
  __shared__ unsigned short Ah[128 * 40];
  __shared__ unsigned short Al[128 * 40];
  __shared__ unsigned short Bh[128 * 40];
  __shared__ unsigned short Bl[128 * 40];
  __shared__ unsigned long long redk[128][2];
  __shared__ float redd[128][2];
  __shared__ int bidx[128];
  __shared__ float dsum[128];

  const int tid = threadIdx.x;
  const int w = tid >> 6, wr = w >> 1, wc = w & 1;
  const int l = tid & 63, l15 = l & 15, lg = l >> 4;
  const int c = blockIdx.y;
  const long m0 = (long)blockIdx.x * BM;
  const float* Ben = en + (size_t)c * 524288;
  const size_t cb_base = (size_t)c * 524288;

  float rrn[16];
#pragma unroll
  for (int fi = 0; fi < 4; fi++)
#pragma unroll
    for (int r = 0; r < 4; r++)
      rrn[fi * 4 + r] = rn[(long)c * 32768 + m0 + wr * 64 + fi * 16 + lg * 4 + r];

  unsigned long long best = 0ULL;   // key: (~flip(dist))<<32 | ~code
  float bestd2 = 1e30f;             // second-best dist so far

  for (int ct = 0; ct < 8; ct++) {
    const int n0 = ct * 128;
    f32x4 acc[4][4];
#pragma unroll
    for (int fi = 0; fi < 4; fi++)
#pragma unroll
      for (int fj = 0; fj < 4; fj++)
#pragma unroll
        for (int r = 0; r < 4; r++) acc[fi][fj][r] = 0.f;

    for (int k0 = 0; k0 < 512; k0 += 32) {
      // stage A: copy pre-split z planes [128][32]
#pragma unroll
      for (int i = 0; i < 2; i++) {
        int q = tid + i * 256;
        int row = q >> 2, kc = (q & 3) * 8;
        size_t g = (size_t)(m0 + row) * 1536 + (size_t)c * 512 + k0 + kc;
        *(uint4*)&Ah[row * 40 + kc] = *(const uint4*)(zh + g);
        *(uint4*)&Al[row * 40 + kc] = *(const uint4*)(zl + g);
      }
      // stage B: pre-split bf16 en tile [128 codes][32 k]
#pragma unroll
      for (int i = 0; i < 2; i++) {
        int q = tid + i * 256;
        int code = q >> 2, kc = (q & 3) * 8;
        size_t g = cb_base + (size_t)(n0 + code) * 512 + (k0 + kc);
        *(uint4*)&Bh[code * 40 + kc] = *(const uint4*)(en_hi + g);
        *(uint4*)&Bl[code * 40 + kc] = *(const uint4*)(en_lo + g);
      }
      __syncthreads();

      short8 bh[4], bl[4];
#pragma unroll
      for (int f = 0; f < 4; f++) {
        int boff = (wc * 64 + f * 16 + l15) * 40 + lg * 8;
        bh[f] = *(const short8*)&Bh[boff];
        bl[f] = *(const short8*)&Bl[boff];
      }
#pragma unroll
      for (int fi = 0; fi < 4; fi++) {
        int aoff = (wr * 64 + fi * 16 + l15) * 40 + lg * 8;
        short8 ah = *(const short8*)&Ah[aoff];
        short8 al = *(const short8*)&Al[aoff];
#pragma unroll
        for (int fj = 0; fj < 4; fj++) {
          acc[fi][fj] = MFMA_BF16(ah, bh[fj], acc[fi][fj]);
          acc[fi][fj] = MFMA_BF16(al, bh[fj], acc[fi][fj]);
          acc[fi][fj] = MFMA_BF16(ah, bl[fj], acc[fi][fj]);
        }
      }
      __syncthreads();
    }

    // per-(fi,r): top-2 over this wave's 4 fj codes, butterfly-merge over l15
#pragma unroll
    for (int fi = 0; fi < 4; fi++) {
      unsigned long long kk[4]; float dd[4];
#pragma unroll
      for (int r = 0; r < 4; r++) {
        float d1 = 1e30f, d2v = 1e30f; int bj = 0;
#pragma unroll
        for (int fj = 0; fj < 4; fj++) {
          float d = qdist(acc[fi][fj][r], rrn[fi * 4 + r]);
          if (d < d1) { d2v = d1; d1 = d; bj = fj; }   // fj asc => code asc
          else if (d < d2v) d2v = d;
        }
        int code = n0 + wc * 64 + bj * 16 + l15;
        kk[r] = ((unsigned long long)(~flip_bits(d1)) << 32) | (unsigned)(~code);
        dd[r] = d2v;
      }
#pragma unroll
      for (int m = 1; m < 16; m <<= 1) {
#pragma unroll
        for (int r = 0; r < 4; r++) {
          unsigned long long ok = __shfl_xor(kk[r], m, 64);
          float od = __shfl_xor(dd[r], m, 64);
          if (ok > kk[r]) { dd[r] = fminf(od, dist_of_key(kk[r])); kk[r] = ok; }
          else dd[r] = fminf(dd[r], dist_of_key(ok));
        }
      }
      if (l15 == 0) {
#pragma unroll
        for (int r = 0; r < 4; r++) {
          int row = wr * 64 + fi * 16 + lg * 4 + r;
          redk[row][wc] = kk[r];
          redd[row][wc] = dd[r];
        }
      }
    }
    __syncthreads();
    if (tid < 128) {
      unsigned long long kA = redk[tid][0]; float dA = redd[tid][0];
      unsigned long long kB = redk[tid][1]; float dB = redd[tid][1];
      unsigned long long km; float m2;
      if (kB > kA) { km = kB; m2 = fminf(dB, dist_of_key(kA)); }
      else         { km = kA; m2 = fminf(dA, dist_of_key(kB)); }
      if (km > best) {
        float oldd = (best == 0ULL) ? 1e30f : dist_of_key(best);
        bestd2 = fminf(oldd, m2);
        best = km;
      } else {
        bestd2 = fminf(bestd2, dist_of_key(km));
      }
    }
    __syncthreads();
  }

  if (tid < 128) {
    const long n = m0 + tid;
    const unsigned code = ~(unsigned)best;
    const float d1 = dist_of_key(best);
    out[CODES_OFF + (unsigned long long)n * 3 + c] = (float)code;
    bidx[tid] = (int)code;
    dsum[tid] = d1;                      // approx d1; lvq error negligible
    if (bestd2 - d1 < TAU_APPROX) {      // approx near-tie: fp32 refine
      int slot = atomicAdd(fc1, 1);
      if (slot < MAXF1) { flags1[2 * slot] = (int)n; flags1[2 * slot + 1] = c; }
    }
  }
  __syncthreads();
  if (tid < 64) dsum[tid] += dsum[tid + 64];
  __syncthreads();
  if (tid < 64) {
    float s = dsum[tid];
#pragma unroll
    for (int off = 32; off; off >>= 1) s += __shfl_xor(s, off);
    if (tid == 0) atomicAdd(lvq, s * (0.25f / (32768.f * 512.f)));
  }
  for (int t = tid; t < 128 * 128; t += 256) {
    int r = t >> 7, d4 = (t & 127) * 4;
    float4 v = *(const float4*)(Ben + (long)bidx[r] * 512 + d4);
    *(float4*)(out + TOKEMB_OFF + (unsigned long long)(m0 + r) * 1536 + c * 512 + d4) = v;
  }
}

// ---------------------------------------------------------------------------
// Tier 1: recompute z row EXACTLY in fp32 from H (out) and Wc, recompute rn,
// rescan all 1024 codes. Reference-exact quantized argmin, tie -> lowest.
__global__ __launch_bounds__(256)
void refine_fp32(const float* __restrict__ H,
                 const float* __restrict__ Wm, const float* __restrict__ bm,
                 const float* __restrict__ Wt, const float* __restrict__ bt,
                 const float* __restrict__ Wp, const float* __restrict__ bp,
                 const float* __restrict__ en,
                 const int* __restrict__ fc1, const int* __restrict__ flags1,
                 int* __restrict__ fc2, int* __restrict__ flags2,
                 float* __restrict__ out)
{
  int nf = *fc1; if (nf > MAXF1) nf = MAXF1;
  const int b = blockIdx.x;
  if (b >= nf) return;
  const int n = flags1[2 * b];
  const int c = flags1[2 * b + 1];
  const int t = threadIdx.x;

  __shared__ float sH[512];
  __shared__ float zs[512];
  __shared__ float sred[256];
  __shared__ unsigned long long wk[4];
  __shared__ float wd2[4];
  __shared__ int fcode;
  __shared__ float srn;

  const float* Wc = (c == 0) ? Wm : (c == 1) ? Wt : Wp;
  const float* bc = (c == 0) ? bm : (c == 1) ? bt : bp;

  sH[t]       = H[(size_t)n * 512 + t];
  sH[t + 256] = H[(size_t)n * 512 + 256 + t];
  __syncthreads();

  { // z = H @ Wc + bc (exact fp32, sequential k chain per output)
    float a0 = 0.f, a1 = 0.f;
    for (int i = 0; i < 512; i++) {
      float h = sH[i];
      a0 = fmaf(h, Wc[(size_t)i * 512 + t], a0);
      a1 = fmaf(h, Wc[(size_t)i * 512 + t + 256], a1);
    }
    float z0 = a0 + bc[t];
    float z1 = a1 + bc[t + 256];
    zs[t] = z0; zs[t + 256] = z1;
    sred[t] = z0 * z0 + z1 * z1;
  }
  __syncthreads();
  for (int s = 128; s > 0; s >>= 1) {
    if (t < s) sred[t] += sred[t + s];
    __syncthreads();
  }
  if (t == 0) srn = 1.f / sqrtf(sred[0] + 1e-12f);
  __syncthreads();
  const float rnv = srn;

  const int wv = t >> 6, lane = t & 63;
  float zlv[8];
#pragma unroll
  for (int m = 0; m < 8; m++) zlv[m] = zs[lane * 8 + m];

  const float* cbase = en + (size_t)c * 524288;
  unsigned long long k1 = 0ULL; float d2 = 1e30f;
  for (int j = 0; j < 256; j++) {
    int k = (j << 2) | wv;                 // wave wv: k == wv (mod 4), asc
    const float* cr = cbase + (size_t)k * 512 + lane * 8;
    float4 c0 = *(const float4*)cr, c1 = *(const float4*)(cr + 4);
    float dt = zlv[0] * c0.x + zlv[1] * c0.y + zlv[2] * c0.z + zlv[3] * c0.w
             + zlv[4] * c1.x + zlv[5] * c1.y + zlv[6] * c1.z + zlv[7] * c1.w;
#pragma unroll
    for (int off = 32; off; off >>= 1) dt += __shfl_xor(dt, off);
    float d = qdist(dt, rnv);
    unsigned long long key =
        ((unsigned long long)(~flip_bits(d)) << 32) | (unsigned)(~k);
    if (key > k1) { d2 = fminf(d2, (k1 == 0ULL) ? 1e30f : dist_of_key(k1)); k1 = key; }
    else d2 = fminf(d2, d);
  }
  if (lane == 0) { wk[wv] = k1; wd2[wv] = d2; }
  __syncthreads();
  if (t == 0) {
    unsigned long long kb = wk[0]; float s2 = wd2[0];
#pragma unroll
    for (int w = 1; w < 4; w++) {
      unsigned long long q = wk[w]; float qd2 = wd2[w];
      if (q > kb) { s2 = fminf(qd2, dist_of_key(kb)); kb = q; }
      else s2 = fminf(s2, dist_of_key(q));
    }
    int code = (int)(~(unsigned)kb);
    float d1 = dist_of_key(kb);
    out[CODES_OFF + (unsigned long long)n * 3 + c] = (float)code;
    fcode = code;
    if (s2 - d1 < TAU_DIST) {            // exact near-tie: fp64 rescue
      int slot = atomicAdd(fc2, 1);
      if (slot < MAXF) { flags2[2 * slot] = n; flags2[2 * slot + 1] = c; }
    }
  }
  __syncthreads();
  const int fk = fcode;
  if (t < 128) {
    const float* er = en + ((size_t)c * 1024 + fk) * 512;
    float4 v = ((const float4*)er)[t];
    *(float4*)(out + TOKEMB_OFF + (unsigned long long)n * 1536 + c * 512 + t * 4) = v;
  }
}

// ---------------------------------------------------------------------------
// Tier 2: fp64 rescue — recompute flagged (row, codebook) from h0 in double,
// apply the reference's fp32 quantization, argmin with lowest-index tie-break.
__global__ __launch_bounds__(256)
void rescue_fp64(const float* __restrict__ h0,
                 const float* __restrict__ W1, const float* __restrict__ b1,
                 const float* __restrict__ W2, const float* __restrict__ b2,
                 const float* __restrict__ Wm, const float* __restrict__ bm,
                 const float* __restrict__ Wt, const float* __restrict__ bt,
                 const float* __restrict__ Wp, const float* __restrict__ bp,
                 const float* __restrict__ cbm, const float* __restrict__ cbt,
                 const float* __restrict__ cbp,
                 const float* __restrict__ en,
                 const int* __restrict__ flag_cnt, const int* __restrict__ flags,
                 float* __restrict__ out)
{
  int nf = *flag_cnt; if (nf > MAXF) nf = MAXF;
  const int b = blockIdx.x;
  if (b >= nf) return;
  const int n = flags[2 * b];
  const int c = flags[2 * b + 1];
  const int t = threadIdx.x;

  __shared__ double s1[512];
  __shared__ double s2[512];
  __shared__ double sred[256];
  __shared__ float sd4[4];
  __shared__ int sk4[4];
  __shared__ double shz;

  const float* Wc = (c == 0) ? Wm : (c == 1) ? Wt : Wp;
  const float* bc = (c == 0) ? bm : (c == 1) ? bt : bp;
  const float* cb = (c == 0) ? cbm : (c == 1) ? cbt : cbp;
  const float* h0r = h0 + (size_t)n * 1024;

  { // h1 = relu(h0 @ W1 + b1)
    double a0 = 0.0, a1 = 0.0;
    for (int i = 0; i < 1024; i++) {
      double h = (double)h0r[i];
      a0 = fma(h, (double)W1[(size_t)i * 512 + t], a0);
      a1 = fma(h, (double)W1[(size_t)i * 512 + t + 256], a1);
    }
    s1[t]       = fmax(a0 + (double)b1[t], 0.0);
    s1[t + 256] = fmax(a1 + (double)b1[t + 256], 0.0);
  }
  __syncthreads();
  { // H = relu(h1 @ W2 + b2)
    double a0 = 0.0, a1 = 0.0;
    for (int i = 0; i < 512; i++) {
      double h = s1[i];
      a0 = fma(h, (double)W2[(size_t)i * 512 + t], a0);
      a1 = fma(h, (double)W2[(size_t)i * 512 + t + 256], a1);
    }
    s2[t]       = fmax(a0 + (double)b2[t], 0.0);
    s2[t + 256] = fmax(a1 + (double)b2[t + 256], 0.0);
  }
  __syncthreads();
  { // z = H @ Wc + bc
    double a0 = 0.0, a1 = 0.0;
    for (int i = 0; i < 512; i++) {
      double h = s2[i];
      a0 = fma(h, (double)Wc[(size_t)i * 512 + t], a0);
      a1 = fma(h, (double)Wc[(size_t)i * 512 + t + 256], a1);
    }
    __syncthreads();
    s1[t]       = a0 + (double)bc[t];
    s1[t + 256] = a1 + (double)bc[t + 256];
  }
  __syncthreads();
  sred[t] = s1[t] * s1[t] + s1[t + 256] * s1[t + 256];
  __syncthreads();
  for (int s = 128; s > 0; s >>= 1) {
    if (t < s) sred[t] += sred[t + s];
    __syncthreads();
  }
  if (t == 0) shz = 1.0 / sqrt(sred[0] + 1e-12);
  __syncthreads();
  const double rz = shz;

  const int wv = t >> 6, lane = t & 63;
  double zl[8];
#pragma unroll
  for (int m = 0; m < 8; m++) zl[m] = s1[lane * 8 + m];
  float bd = 1e30f; int bkk = 1 << 30;
  for (int j = 0; j < 256; j++) {
    int k = (j << 2) | wv;
    const float* cr = cb + (size_t)k * 512 + lane * 8;
    float4 c0 = *(const float4*)cr, c1 = *(const float4*)(cr + 4);
    double x0 = c0.x, x1 = c0.y, x2 = c0.z, x3 = c0.w;
    double x4 = c1.x, x5 = c1.y, x6 = c1.z, x7 = c1.w;
    double dt = zl[0]*x0 + zl[1]*x1 + zl[2]*x2 + zl[3]*x3
              + zl[4]*x4 + zl[5]*x5 + zl[6]*x6 + zl[7]*x7;
    double nc = x0*x0 + x1*x1 + x2*x2 + x3*x3 + x4*x4 + x5*x5 + x6*x6 + x7*x7;
#pragma unroll
    for (int off = 32; off; off >>= 1) {
      dt += __shfl_xor(dt, off);
      nc += __shfl_xor(nc, off);
    }
    double sim64 = dt * rz * (1.0 / sqrt(nc + 1e-12));
    float s32 = (float)sim64;
    float d32 = __fadd_rn(2.0f, -__fmul_rn(2.0f, s32));
    if (d32 < bd) { bd = d32; bkk = k; }
  }
  if (lane == 0) { sd4[wv] = bd; sk4[wv] = bkk; }
  __syncthreads();
  if (t == 0) {
    float d = sd4[0]; int k = sk4[0];
#pragma unroll
    for (int w = 1; w < 4; w++)
      if (sd4[w] < d || (sd4[w] == d && sk4[w] < k)) { d = sd4[w]; k = sk4[w]; }
    sk4[0] = k;
    out[CODES_OFF + (unsigned long long)n * 3 + c] = (float)k;
  }
  __syncthreads();
  const int fk = sk4[0];
  if (t < 128) {
    const float* er = en + ((size_t)c * 1024 + fk) * 512;
    float4 v = ((const float4*)er)[t];
    *(float4*)(out + TOKEMB_OFF + (unsigned long long)n * 1536 + c * 512 + t * 4) = v;
  }
}

// ---------------------------------------------------------------------------
// rn = 1/||z~|| from the hi/lo planes (z~ = hi + lo reconstructed).
__global__ __launch_bounds__(256)
void row_rnorm(const unsigned short* __restrict__ zh,
               const unsigned short* __restrict__ zl,
               float* __restrict__ rn)
{
  const int lane = threadIdx.x & 63;
  const long r = (long)blockIdx.x * 4 + (threadIdx.x >> 6);
  const int cc = (int)(r >> 15), n = (int)(r & 32767);
  const size_t base = (size_t)n * 1536 + (size_t)cc * 512 + lane * 8;
  uint4 h = *(const uint4*)(zh + base);
  uint4 lo = *(const uint4*)(zl + base);
  float s = 0.f;
  const unsigned hw[4] = {h.x, h.y, h.z, h.w};
  const unsigned lw[4] = {lo.x, lo.y, lo.z, lo.w};
#pragma unroll
  for (int i = 0; i < 4; i++) {
    float ze = __uint_as_float(hw[i] << 16) + __uint_as_float(lw[i] << 16);
    float zo = __uint_as_float(hw[i] & 0xFFFF0000u) + __uint_as_float(lw[i] & 0xFFFF0000u);
    s = fmaf(ze, ze, s);
    s = fmaf(zo, zo, s);
  }
#pragma unroll
  for (int off = 32; off; off >>= 1) s += __shfl_xor(s, off);
  if (lane == 0) rn[r] = 1.f / sqrtf(s + 1e-12f);
}

// normalize codebooks -> en (fp32) and pre-split bf16 hi/lo for the MFMA sim
__global__ __launch_bounds__(256)
void cb_norm(const float* __restrict__ cbm, const float* __restrict__ cbt,
             const float* __restrict__ cbp, float* __restrict__ en,
             unsigned short* __restrict__ en_hi, unsigned short* __restrict__ en_lo)
{
  const int lane = threadIdx.x & 63;
  const long r = (long)blockIdx.x * 4 + (threadIdx.x >> 6);
  const int cc = (int)(r >> 10), k = (int)(r & 1023);
  const float* cb = (cc == 0) ? cbm : (cc == 1) ? cbt : cbp;
  const float* p = cb + (long)k * 512 + lane * 8;
  float4 v0 = *(const float4*)p, v1 = *(const float4*)(p + 4);
  float s = v0.x * v0.x + v0.y * v0.y + v0.z * v0.z + v0.w * v0.w
          + v1.x * v1.x + v1.y * v1.y + v1.z * v1.z + v1.w * v1.w;
#pragma unroll
  for (int off = 32; off; off >>= 1) s += __shfl_xor(s, off);
  float sc = 1.f / sqrtf(s + 1e-12f);
  v0.x *= sc; v0.y *= sc; v0.z *= sc; v0.w *= sc;
  v1.x *= sc; v1.y *= sc; v1.z *= sc; v1.w *= sc;
  const size_t g = (size_t)cc * 524288 + (size_t)k * 512 + lane * 8;
  float* q = en + g;
  *(float4*)q = v0; *(float4*)(q + 4) = v1;
  unsigned h[8], lo[8];
  split2(v0.x, h[0], lo[0]); split2(v0.y, h[1], lo[1]);
  split2(v0.z, h[2], lo[2]); split2(v0.w, h[3], lo[3]);
  split2(v1.x, h[4], lo[4]); split2(v1.y, h[5], lo[5]);
  split2(v1.z, h[6], lo[6]); split2(v1.w, h[7], lo[7]);
  uint4 hp, lp;
  hp.x = h[0] | (h[1] << 16);  hp.y = h[2] | (h[3] << 16);
  hp.z = h[4] | (h[5] << 16);  hp.w = h[6] | (h[7] << 16);
  lp.x = lo[0] | (lo[1] << 16); lp.y = lo[2] | (lo[3] << 16);
  lp.z = lo[4] | (lo[5] << 16); lp.w = lo[6] | (lo[7] << 16);
  *(uint4*)(en_hi + g) = hp;
  *(uint4*)(en_lo + g) = lp;
}

__global__ __launch_bounds__(256)
void logits_alpha(const float* __restrict__ H, const float* __restrict__ Wk,
                  const float* __restrict__ bk, float* __restrict__ alpha)
{
  const int lane = threadIdx.x & 63;
  const long n = (long)blockIdx.x * 4 + (threadIdx.x >> 6);
  const float* p = H + n * 512 + lane * 8;
  const float* w = Wk + lane * 8;
  float4 a0 = *(const float4*)p, a1 = *(const float4*)(p + 4);
  float4 w0 = *(const float4*)w, w1 = *(const float4*)(w + 4);
  float s = a0.x * w0.x + a0.y * w0.y + a0.z * w0.z + a0.w * w0.w
          + a1.x * w1.x + a1.y * w1.y + a1.z * w1.z + a1.w * w1.w;
#pragma unroll
  for (int off = 32; off; off >>= 1) s += __shfl_xor(s, off);
  if (lane == 0) alpha[n] = 1.f / (1.f + expf(-(s + bk[0])));
}

__global__ __launch_bounds__(1024)
void topk32(const float* __restrict__ alpha, float* __restrict__ out)
{
  __shared__ unsigned long long sk[1024];
  const int tid = threadIdx.x;
  unsigned long long prev = ~0ULL;
  for (int it = 0; it < 32; it++) {
    unsigned long long best = 0;
#pragma unroll 4
    for (int i = tid; i < 32768; i += 1024) {
      unsigned long long key =
          ((unsigned long long)flip_bits(alpha[i]) << 32) | (unsigned)(~i);
      if (key < prev && key > best) best = key;
    }
    sk[tid] = best;
    __syncthreads();
    for (int s = 512; s > 0; s >>= 1) {
      if (tid < s) { unsigned long long q = sk[tid + s]; if (q > sk[tid]) sk[tid] = q; }
      __syncthreads();
    }
    unsigned long long sel = sk[0];
    __syncthreads();
    if (tid == 0) out[it] = (float)(~(unsigned)sel);
    prev = sel;
  }
}

extern "C" void kernel_launch(void* const* d_in, const int* in_sizes, int n_in,
                              void* d_out, int out_size, void* d_ws, size_t ws_size,
                              hipStream_t stream)
{
  (void)in_sizes; (void)n_in; (void)out_size; (void)ws_size;
  const float* h0  = (const float*)d_in[0];
  const float* W1  = (const float*)d_in[1];
  const float* b1  = (const float*)d_in[2];
  const float* W2  = (const float*)d_in[3];
  const float* b2  = (const float*)d_in[4];
  const float* Wm  = (const float*)d_in[5];
  const float* bm  = (const float*)d_in[6];
  const float* Wt  = (const float*)d_in[7];
  const float* bt  = (const float*)d_in[8];
  const float* Wp  = (const float*)d_in[9];
  const float* bp  = (const float*)d_in[10];
  const float* cbm = (const float*)d_in[11];
  const float* cbt = (const float*)d_in[12];
  const float* cbp = (const float*)d_in[13];
  const float* Wk  = (const float*)d_in[14];
  const float* bk  = (const float*)d_in[15];
  float* out = (float*)d_out;
  float* ws  = (float*)d_ws;

  // late-phase planes
  unsigned short* zh = (unsigned short*)ws;                 // [32768][1536]
  unsigned short* zl = (unsigned short*)ws + 50331648ULL;   // [32768][1536]
  // early-phase overlays inside the z region (dead before planes written)
  float* h1 = ws;                                           // [32768,512] f32
  unsigned short* W1h = (unsigned short*)ws + 33554432ULL;  // byte 64MB, 1MB
  unsigned short* W1l = W1h + 524288ULL;
  unsigned short* W2h = W1l + 524288ULL;                    // 0.5MB
  unsigned short* W2l = W2h + 262144ULL;
  // persistent region
  float* en = ws + 50331648ULL;      // [3,1024,512] f32
  float* rn = ws + 51904512ULL;      // [3*32768]
  float* al = ws + 52002816ULL;      // [32768]
  int* fc1    = (int*)(ws + 52035584ULL);
  int* flags1 = (int*)(ws + 52035585ULL);            // [MAXF1][2]
  int* fc2    = (int*)(ws + 52060161ULL);
  int* flags2 = (int*)(ws + 52060162ULL);            // [MAXF][2]
  unsigned short* en_hi = (unsigned short*)(ws + 52068356ULL);  // [3*1024*512]
  unsigned short* en_lo = (unsigned short*)(ws + 52854788ULL);  // [3*1024*512]
  unsigned short* Wh = (unsigned short*)(ws + 53641220ULL);     // [3][512][512]
  unsigned short* Wl = (unsigned short*)(ws + 54034436ULL);     // [3][512][512]
  float* H  = out;
  float* lvq = out + LVQ_OFF;

  hipMemsetAsync(lvq, 0, sizeof(float), stream);
  hipMemsetAsync(fc1, 0, sizeof(int), stream);
  hipMemsetAsync(fc2, 0, sizeof(int), stream);

  // weight pre-splits (transposed planes)
  wsplit_g<<<256, 256, 0, stream>>>(W1, W1h, W1l, 1024);
  wsplit_g<<<128, 256, 0, stream>>>(W2, W2h, W2l, 512);
  wsplit_g<<<128, 256, 0, stream>>>(Wm, Wh + 0 * 262144, Wl + 0 * 262144, 512);
  wsplit_g<<<128, 256, 0, stream>>>(Wt, Wh + 1 * 262144, Wl + 1 * 262144, 512);
  wsplit_g<<<128, 256, 0, stream>>>(Wp, Wh + 2 * 262144, Wl + 2 * 262144, 512);

  // encoder on MFMA: h1 = relu(h0@W1+b1), H = relu(h1@W2+b2)
  mfma_gemm<1, 0><<<256, 512, 0, stream>>>(h0, 1024, 1024, W1h, W1l, b1,
                                           h1, 512, nullptr, nullptr, 0, 0);
  mfma_gemm<1, 0><<<256, 512, 0, stream>>>(h1, 512, 512, W2h, W2l, b2,
                                           H, 512, nullptr, nullptr, 0, 0);

  // z projections on MFMA, written directly as bf16 hi/lo planes
  mfma_gemm<0, 1><<<256, 512, 0, stream>>>(H, 512, 512, Wh + 0 * 262144,
                                           Wl + 0 * 262144, bm, nullptr, 0,
                                           zh, zl, 1536, 0);
  mfma_gemm<0, 1><<<256, 512, 0, stream>>>(H, 512, 512, Wh + 1 * 262144,
                                           Wl + 1 * 262144, bt, nullptr, 0,
                                           zh, zl, 1536, 512);
  mfma_gemm<0, 1><<<256, 512, 0, stream>>>(H, 512, 512, Wh + 2 * 262144,
                                           Wl + 2 * 262144, bp, nullptr, 0,
                                           zh, zl, 1536, 1024);

  row_rnorm<<<24576, 256, 0, stream>>>(zh, zl, rn);
  cb_norm<<<768, 256, 0, stream>>>(cbm, cbt, cbp, en, en_hi, en_lo);
  sim_argmax<<<dim3(256, 3), 256, 0, stream>>>(zh, zl, en, en_hi, en_lo, rn, out, lvq,
                                               fc1, flags1);
  refine_fp32<<<MAXF1, 256, 0, stream>>>(H, Wm, bm, Wt, bt, Wp, bp, en,
                                         fc1, flags1, fc2, flags2, out);
  rescue_fp64<<<MAXF, 256, 0, stream>>>(h0, W1, b1, W2, b2, Wm, bm, Wt, bt, Wp, bp,
                                        cbm, cbt, cbp, en, fc2, flags2, out);
  logits_alpha<<<8192, 256, 0, stream>>>(H, Wk, bk, al);
  topk32<<<1, 1024, 0, stream>>>(al, out + KEYIDX_OFF);
}

// Round 4
// 2064.766 us; speedup vs baseline: 1.6962x; 1.1160x over previous
//
#include <hip/hip_runtime.h>

// Problem: N=32768 rows, Din=1024, HID=512, K=1024 codes, 3 codebooks.
// d_out layout (float32):
//   H @ 0 [32768,512] | codes @ 16777216 [32768,3] | key_idx @ 16875520 [32]
//   token_emb @ 16875552 [32768,1536] | L_vq @ 67207200 scalar
// ws layout (bytes):
//   [0, 96MB)    zh plane (ushort [32768][1536])    -- late phase
//   [96, 192MB)  zl plane                            -- late phase
//     early phase overlays (dead before Z kernels write planes):
//       h1 fp32 [32768,512] @ 0 (64MB)
//       W1h @ 64MB (1MB) | W1l @ 65MB | W2h @ 66MB (0.5MB) | W2l @ 66.5MB
//   en @ float-ofs 50331648 (3*1024*512 f32), rn @ 51904512 (98304),
//   alpha @ 52002816, fc1 @ 52035584, fc2 @ +1, flags1 @ +2 (2*12288),
//   flags2 @ +2+24576 (2*4096),
//   en_hi @ 52068356 (ushort 3*1024*512), en_lo @ 52854788,
//   Wh @ 53641220 (ushort [3][512][512] transposed), Wl @ 54034436
//
// NUMERICS FUNNEL: reference computes dist = 2 - 2*sim in fp32 (bins of
// ulp(2)/2), argmin ties -> lowest code.
//   tier 0: ALL gemms on MFMA via bf16x3 split (hi*hi + lo*hi + hi*lo, fp32
//           accum). z stored as bf16 hi/lo planes. sim matrix on MFMA;
//           certified mfma-sim term <= 2.4e-5. Flag approx-gap < 1.25e-4.
//   tier 1: refine_fp32 recomputes z row EXACTLY in fp32 from our H (out),
//           recomputes rn, rescans all 1024 codes -> reference-exact
//           quantized argmin; re-flags exact-gap < TAU_DIST for fp64 rescue.
//   tier 2: rescue_fp64: fp64 from h0 (reference truth) -> quantized truth.
//
// PERF HISTORY: r0 3502 (VALU gemms) -> r1 2867 (mfma sim) -> r2 2494
// (z planes) -> r3 2304 (all gemms mfma, but 8-wave/100KB LDS = 1 block/CU).
// r4: retile gemms to 4-wave/128x128/40KB (3-4 blocks/CU, same structure as
// sim_argmax which gets cross-block overlap), fuse wsplit, reg-cache topk.

#define BM 128
#define MAXF 4096          // fp64 rescue capacity
#define MAXF1 12288        // fp32 refine capacity
#define TAU_DIST 2e-5f     // exact-gap threshold -> fp64 rescue
#define TAU_APPROX 1.25e-4f // approx-gap threshold -> fp32 refine

#define CODES_OFF   16777216ULL
#define KEYIDX_OFF  16875520ULL
#define TOKEMB_OFF  16875552ULL
#define LVQ_OFF     67207200ULL

typedef __attribute__((ext_vector_type(8))) short short8;   // 8 bf16 (4 VGPR)
typedef __attribute__((ext_vector_type(4))) float f32x4;

#define MFMA_BF16(a, b, c) __builtin_amdgcn_mfma_f32_16x16x32_bf16(a, b, c, 0, 0, 0)

__device__ __forceinline__ unsigned flip_bits(float x) {
  unsigned b = __float_as_uint(x);
  return b ^ ((unsigned)((int)b >> 31) | 0x80000000u);
}
__device__ __forceinline__ float unflip_bits(unsigned ob) {
  unsigned b = (ob & 0x80000000u) ? (ob ^ 0x80000000u) : ~ob;
  return __uint_as_float(b);
}
// reference-exact dist: fl32(2 - 2*fl32(sim)); __f*_rn blocks fma contraction
__device__ __forceinline__ float qdist(float dot, float rnv) {
  float sim = __fmul_rn(dot, rnv);
  return __fadd_rn(2.0f, -__fmul_rn(2.0f, sim));
}
__device__ __forceinline__ float dist_of_key(unsigned long long q) {
  return unflip_bits(~(unsigned)(q >> 32));
}
// RNE bf16 two-term split: x = hi + lo + r, |r| <= 2^-18 |x|.
__device__ __forceinline__ void split2(float x, unsigned& h, unsigned& l) {
  unsigned b = __float_as_uint(x);
  unsigned hb = (b + 0x7FFFu + ((b >> 16) & 1u)) & 0xFFFF0000u;
  h = hb >> 16;
  float r = x - __uint_as_float(hb);
  unsigned cbits = __float_as_uint(r);
  l = (cbits + 0x7FFFu + ((cbits >> 16) & 1u)) >> 16;
}

// ---------------------------------------------------------------------------
// Split + transpose ALL weight matrices -> bf16 hi/lo planes [512 n][K k]
// in one launch. W1 (K=1024) then W2, Wm, Wt, Wp (K=512).
__global__ __launch_bounds__(256)
void wsplit_all(const float* __restrict__ W1, const float* __restrict__ W2,
                const float* __restrict__ Wm, const float* __restrict__ Wt,
                const float* __restrict__ Wp,
                unsigned short* __restrict__ w1h, unsigned short* __restrict__ w1l,
                unsigned short* __restrict__ w2h, unsigned short* __restrict__ w2l,
                unsigned short* __restrict__ wh,  unsigned short* __restrict__ wl)
{
  int t = blockIdx.x * 256 + threadIdx.x;      // 65536 + 4*32768 = 196608
  const float* W; unsigned short *dh, *dl; int n, kg, K;
  if (t < 65536) {
    W = W1; dh = w1h; dl = w1l; K = 1024;
    n = t >> 7; kg = (t & 127) * 8;
  } else {
    int idx = t - 65536;
    int w = idx >> 15, rem = idx & 32767;
    n = rem >> 6; kg = (rem & 63) * 8; K = 512;
    if (w == 0)      { W = W2; dh = w2h;          dl = w2l; }
    else if (w == 1) { W = Wm; dh = wh;           dl = wl; }
    else if (w == 2) { W = Wt; dh = wh + 262144;  dl = wl + 262144; }
    else             { W = Wp; dh = wh + 524288;  dl = wl + 524288; }
  }
  unsigned h[8], l[8];
#pragma unroll
  for (int i = 0; i < 8; i++) {
    float v = W[(size_t)(kg + i) * 512 + n];   // W is [k][n]
    split2(v, h[i], l[i]);
  }
  uint4 hp, lp;
  hp.x = h[0] | (h[1] << 16); hp.y = h[2] | (h[3] << 16);
  hp.z = h[4] | (h[5] << 16); hp.w = h[6] | (h[7] << 16);
  lp.x = l[0] | (l[1] << 16); lp.y = l[2] | (l[3] << 16);
  lp.z = l[4] | (l[5] << 16); lp.w = l[6] | (l[7] << 16);
  size_t g = (size_t)n * K + kg;
  *(uint4*)(dh + g) = hp;
  *(uint4*)(dl + g) = lp;
}

// ---------------------------------------------------------------------------
// Unified bf16x3 MFMA GEMM, 128x128 tile, 4 waves, 40KB LDS (3-4 blocks/CU
// like sim_argmax). grid (M/128, N/128). Inner loop == sim_argmax's verified
// k-step. OUTPLANES=0: fp32 C. OUTPLANES=1: bf16 hi/lo planes via LDS stage.
template<int RELU, int OUTPLANES>
__global__ __launch_bounds__(256)
void mfma_gemm128(const float* __restrict__ A, int lda, int K,
                  const unsigned short* __restrict__ wh,
                  const unsigned short* __restrict__ wl,
                  const float* __restrict__ bias,
                  float* __restrict__ Cf, int ldc,
                  unsigned short* __restrict__ zh, unsigned short* __restrict__ zl,
                  int ldz, int colOff)
{
  __shared__ __align__(16) unsigned char smem[40960];
  unsigned short* Ah = (unsigned short*)smem;          // [128][40]
  unsigned short* Al = Ah + 5120;
  unsigned short* Bh = Al + 5120;
  unsigned short* Bl = Bh + 5120;

  const int tid = threadIdx.x;
  const int w = tid >> 6, wr = w >> 1, wc = w & 1;
  const int l = tid & 63, l15 = l & 15, lg = l >> 4;
  const long m0 = (long)blockIdx.x * BM;
  const int n0 = blockIdx.y * 128;

  f32x4 acc[4][4];
#pragma unroll
  for (int fi = 0; fi < 4; fi++)
#pragma unroll
    for (int fj = 0; fj < 4; fj++)
#pragma unroll
      for (int r = 0; r < 4; r++) acc[fi][fj][r] = 0.f;

  for (int k0 = 0; k0 < K; k0 += 32) {
    // stage A: fp32 tile [128][32] -> hi/lo bf16 LDS (split on the fly)
#pragma unroll
    for (int i = 0; i < 4; i++) {
      int f4 = tid + i * 256;
      int row = f4 >> 3, kc = (f4 & 7) * 4;
      float4 v = *(const float4*)(A + (m0 + row) * lda + k0 + kc);
      unsigned hx, lx, hy, ly, hz, lz, hw, lw;
      split2(v.x, hx, lx); split2(v.y, hy, ly);
      split2(v.z, hz, lz); split2(v.w, hw, lw);
      uint2 hp, lp;
      hp.x = hx | (hy << 16); hp.y = hz | (hw << 16);
      lp.x = lx | (ly << 16); lp.y = lz | (lw << 16);
      *(uint2*)&Ah[row * 40 + kc] = hp;
      *(uint2*)&Al[row * 40 + kc] = lp;
    }
    // stage B: pre-split W planes [128 n][32 k] (pure copy)
#pragma unroll
    for (int i = 0; i < 2; i++) {
      int q = tid + i * 256;
      int code = q >> 2, kc = (q & 3) * 8;
      size_t g = (size_t)(n0 + code) * K + k0 + kc;
      *(uint4*)&Bh[code * 40 + kc] = *(const uint4*)(wh + g);
      *(uint4*)&Bl[code * 40 + kc] = *(const uint4*)(wl + g);
    }
    __syncthreads();

    short8 bh[4], bl[4];
#pragma unroll
    for (int f = 0; f < 4; f++) {
      int boff = (wc * 64 + f * 16 + l15) * 40 + lg * 8;
      bh[f] = *(const short8*)&Bh[boff];
      bl[f] = *(const short8*)&Bl[boff];
    }
#pragma unroll
    for (int fi = 0; fi < 4; fi++) {
      int aoff = (wr * 64 + fi * 16 + l15) * 40 + lg * 8;
      short8 ah = *(const short8*)&Ah[aoff];
      short8 al = *(const short8*)&Al[aoff];
#pragma unroll
      for (int fj = 0; fj < 4; fj++) {
        acc[fi][fj] = MFMA_BF16(ah, bh[fj], acc[fi][fj]);
        acc[fi][fj] = MFMA_BF16(al, bh[fj], acc[fi][fj]);
        acc[fi][fj] = MFMA_BF16(ah, bl[fj], acc[fi][fj]);
      }
    }
    __syncthreads();
  }

  float bcv[4];
#pragma unroll
  for (int fj = 0; fj < 4; fj++) bcv[fj] = bias[n0 + wc * 64 + fj * 16 + l15];

  if (OUTPLANES == 0) {
    // direct fp32 stores: 16 consecutive lanes cover 16 consecutive cols
#pragma unroll
    for (int fi = 0; fi < 4; fi++)
#pragma unroll
      for (int fj = 0; fj < 4; fj++) {
        int col = n0 + wc * 64 + fj * 16 + l15;
#pragma unroll
        for (int r = 0; r < 4; r++) {
          long row = m0 + wr * 64 + fi * 16 + lg * 4 + r;
          float v = acc[fi][fj][r] + bcv[fj];
          if (RELU) v = fmaxf(v, 0.f);
          Cf[row * (long)ldc + col] = v;
        }
      }
  } else {
    // LDS-staged plane writes: 2 phases ({hi,lo}), [128][128] ushort = 32KB
    unsigned short* ep = (unsigned short*)smem;
#pragma unroll
    for (int pl = 0; pl < 2; pl++) {
#pragma unroll
      for (int fi = 0; fi < 4; fi++)
#pragma unroll
        for (int fj = 0; fj < 4; fj++) {
          int lcol = wc * 64 + fj * 16 + l15;
#pragma unroll
          for (int r = 0; r < 4; r++) {
            int lrow = wr * 64 + fi * 16 + lg * 4 + r;
            float v = acc[fi][fj][r] + bcv[fj];
            unsigned h, lo;
            split2(v, h, lo);
            ep[lrow * 128 + lcol] = (unsigned short)(pl ? lo : h);
          }
        }
      __syncthreads();
      unsigned short* dst = pl ? zl : zh;
      for (int u = tid; u < 2048; u += 256) {
        int row = u >> 4, c8 = (u & 15) * 8;
        size_t g = (size_t)(m0 + row) * ldz + colOff + n0 + c8;
        *(uint4*)(dst + g) = *(const uint4*)(ep + row * 128 + c8);
      }
      __syncthreads();
    }
  }
}

// ---------------------------------------------------------------------------
// Tier 0: MFMA bf16x3 sim + argmin over quantized dist, tie -> lowest code.
// grid (256, 3), block 256 (4 waves, 2x2 wave grid, 64x64 per wave).
__global__ __launch_bounds__(256)
void sim_argmax(const unsigned short* __restrict__ zh,
                const unsigned short* __restrict__ zl,
                const float* __restrict__ en,
                const unsigned short* __restrict__ en_hi,
                const unsigned short* __restrict__ en_lo,
                const float* __restrict__ rn,
                float* __restrict__ out,
                float* __restrict__ lvq,
                int* __restrict__ fc1,
                int* __restrict__ flags1)
{
  __shared__ unsigned short Ah[128 * 40];
  __shared__ unsigned short Al[128 * 40];
  __shared__ unsigned short Bh[128 * 40];
  __shared__ unsigned short Bl[128 * 40];
  __shared__ unsigned long long redk[128][2];
  __shared__ float redd[128][2];
  __shared__ int bidx[128];
  __shared__ float dsum[128];

  const int tid = threadIdx.x;
  const int w = tid >> 6, wr = w >> 1, wc = w & 1;
  const int l = tid & 63, l15 = l & 15, lg = l >> 4;
  const int c = blockIdx.y;
  const long m0 = (long)blockIdx.x * BM;
  const float* Ben = en + (size_t)c * 524288;
  const size_t cb_base = (size_t)c * 524288;

  float rrn[16];
#pragma unroll
  for (int fi = 0; fi < 4; fi++)
#pragma unroll
    for (int r = 0; r < 4; r++)
      rrn[fi * 4 + r] = rn[(long)c * 32768 + m0 + wr * 64 + fi * 16 + lg * 4 + r];

  unsigned long long best = 0ULL;   // key: (~flip(dist))<<32 | ~code
  float bestd2 = 1e30f;             // second-best dist so far

  for (int ct = 0; ct < 8; ct++) {
    const int n0 = ct * 128;
    f32x4 acc[4][4];
#pragma unroll
    for (int fi = 0; fi < 4; fi++)
#pragma unroll
      for (int fj = 0; fj < 4; fj++)
#pragma unroll
        for (int r = 0; r < 4; r++) acc[fi][fj][r] = 0.f;

    for (int k0 = 0; k0 < 512; k0 += 32) {
      // stage A: copy pre-split z planes [128][32]
#pragma unroll
      for (int i = 0; i < 2; i++) {
        int q = tid + i * 256;
        int row = q >> 2, kc = (q & 3) * 8;
        size_t g = (size_t)(m0 + row) * 1536 + (size_t)c * 512 + k0 + kc;
        *(uint4*)&Ah[row * 40 + kc] = *(const uint4*)(zh + g);
        *(uint4*)&Al[row * 40 + kc] = *(const uint4*)(zl + g);
      }
      // stage B: pre-split bf16 en tile [128 codes][32 k]
#pragma unroll
      for (int i = 0; i < 2; i++) {
        int q = tid + i * 256;
        int code = q >> 2, kc = (q & 3) * 8;
        size_t g = cb_base + (size_t)(n0 + code) * 512 + (k0 + kc);
        *(uint4*)&Bh[code * 40 + kc] = *(const uint4*)(en_hi + g);
        *(uint4*)&Bl[code * 40 + kc] = *(const uint4*)(en_lo + g);
      }
      __syncthreads();

      short8 bh[4], bl[4];
#pragma unroll
      for (int f = 0; f < 4; f++) {
        int boff = (wc * 64 + f * 16 + l15) * 40 + lg * 8;
        bh[f] = *(const short8*)&Bh[boff];
        bl[f] = *(const short8*)&Bl[boff];
      }
#pragma unroll
      for (int fi = 0; fi < 4; fi++) {
        int aoff = (wr * 64 + fi * 16 + l15) * 40 + lg * 8;
        short8 ah = *(const short8*)&Ah[aoff];
        short8 al = *(const short8*)&Al[aoff];
#pragma unroll
        for (int fj = 0; fj < 4; fj++) {
          acc[fi][fj] = MFMA_BF16(ah, bh[fj], acc[fi][fj]);
          acc[fi][fj] = MFMA_BF16(al, bh[fj], acc[fi][fj]);
          acc[fi][fj] = MFMA_BF16(ah, bl[fj], acc[fi][fj]);
        }
      }
      __syncthreads();
    }

    // per-(fi,r): top-2 over this wave's 4 fj codes, butterfly-merge over l15
#pragma unroll
    for (int fi = 0; fi < 4; fi++) {
      unsigned long long kk[4]; float dd[4];
#pragma unroll
      for (int r = 0; r < 4; r++) {
        float d1 = 1e30f, d2v = 1e30f; int bj = 0;
#pragma unroll
        for (int fj = 0; fj < 4; fj++) {
          float d = qdist(acc[fi][fj][r], rrn[fi * 4 + r]);
          if (d < d1) { d2v = d1; d1 = d; bj = fj; }   // fj asc => code asc
          else if (d < d2v) d2v = d;
        }
        int code = n0 + wc * 64 + bj * 16 + l15;
        kk[r] = ((unsigned long long)(~flip_bits(d1)) << 32) | (unsigned)(~code);
        dd[r] = d2v;
      }
#pragma unroll
      for (int m = 1; m < 16; m <<= 1) {
#pragma unroll
        for (int r = 0; r < 4; r++) {
          unsigned long long ok = __shfl_xor(kk[r], m, 64);
          float od = __shfl_xor(dd[r], m, 64);
          if (ok > kk[r]) { dd[r] = fminf(od, dist_of_key(kk[r])); kk[r] = ok; }
          else dd[r] = fminf(dd[r], dist_of_key(ok));
        }
      }
      if (l15 == 0) {
#pragma unroll
        for (int r = 0; r < 4; r++) {
          int row = wr * 64 + fi * 16 + lg * 4 + r;
          redk[row][wc] = kk[r];
          redd[row][wc] = dd[r];
        }
      }
    }
    __syncthreads();
    if (tid < 128) {
      unsigned long long kA = redk[tid][0]; float dA = redd[tid][0];
      unsigned long long kB = redk[tid][1]; float dB = redd[tid][1];
      unsigned long long km; float m2;
      if (kB > kA) { km = kB; m2 = fminf(dB, dist_of_key(kA)); }
      else         { km = kA; m2 = fminf(dA, dist_of_key(kB)); }
      if (km > best) {
        float oldd = (best == 0ULL) ? 1e30f : dist_of_key(best);
        bestd2 = fminf(oldd, m2);
        best = km;
      } else {
        bestd2 = fminf(bestd2, dist_of_key(km));
      }
    }
    __syncthreads();
  }

  if (tid < 128) {
    const long n = m0 + tid;
    const unsigned code = ~(unsigned)best;
    const float d1 = dist_of_key(best);
    out[CODES_OFF + (unsigned long long)n * 3 + c] = (float)code;
    bidx[tid] = (int)code;
    dsum[tid] = d1;                      // approx d1; lvq error negligible
    if (bestd2 - d1 < TAU_APPROX) {      // approx near-tie: fp32 refine
      int slot = atomicAdd(fc1, 1);
      if (slot < MAXF1) { flags1[2 * slot] = (int)n; flags1[2 * slot + 1] = c; }
    }
  }
  __syncthreads();
  if (tid < 64) dsum[tid] += dsum[tid + 64];
  __syncthreads();
  if (tid < 64) {
    float s = dsum[tid];
#pragma unroll
    for (int off = 32; off; off >>= 1) s += __shfl_xor(s, off);
    if (tid == 0) atomicAdd(lvq, s * (0.25f / (32768.f * 512.f)));
  }
  for (int t = tid; t < 128 * 128; t += 256) {
    int r = t >> 7, d4 = (t & 127) * 4;
    float4 v = *(const float4*)(Ben + (long)bidx[r] * 512 + d4);
    *(float4*)(out + TOKEMB_OFF + (unsigned long long)(m0 + r) * 1536 + c * 512 + d4) = v;
  }
}

// ---------------------------------------------------------------------------
// Tier 1: recompute z row EXACTLY in fp32 from H (out) and Wc, recompute rn,
// rescan all 1024 codes. Reference-exact quantized argmin, tie -> lowest.
__global__ __launch_bounds__(256)
void refine_fp32(const float* __restrict__ H,
                 const float* __restrict__ Wm, const float* __restrict__ bm,
                 const float* __restrict__ Wt, const float* __restrict__ bt,
                 const float* __restrict__ Wp, const float* __restrict__ bp,
                 const float* __restrict__ en,
                 const int* __restrict__ fc1, const int* __restrict__ flags1,
                 int* __restrict__ fc2, int* __restrict__ flags2,
                 float* __restrict__ out)
{
  int nf = *fc1; if (nf > MAXF1) nf = MAXF1;
  const int b = blockIdx.x;
  if (b >= nf) return;
  const int n = flags1[2 * b];
  const int c = flags1[2 * b + 1];
  const int t = threadIdx.x;

  __shared__ float sH[512];
  __shared__ float zs[512];
  __shared__ float sred[256];
  __shared__ unsigned long long wk[4];
  __shared__ float wd2[4];
  __shared__ int fcode;
  __shared__ float srn;

  const float* Wc = (c == 0) ? Wm : (c == 1) ? Wt : Wp;
  const float* bc = (c == 0) ? bm : (c == 1) ? bt : bp;

  sH[t]       = H[(size_t)n * 512 + t];
  sH[t + 256] = H[(size_t)n * 512 + 256 + t];
  __syncthreads();

  { // z = H @ Wc + bc (exact fp32, sequential k chain per output)
    float a0 = 0.f, a1 = 0.f;
    for (int i = 0; i < 512; i++) {
      float h = sH[i];
      a0 = fmaf(h, Wc[(size_t)i * 512 + t], a0);
      a1 = fmaf(h, Wc[(size_t)i * 512 + t + 256], a1);
    }
    float z0 = a0 + bc[t];
    float z1 = a1 + bc[t + 256];
    zs[t] = z0; zs[t + 256] = z1;
    sred[t] = z0 * z0 + z1 * z1;
  }
  __syncthreads();
  for (int s = 128; s > 0; s >>= 1) {
    if (t < s) sred[t] += sred[t + s];
    __syncthreads();
  }
  if (t == 0) srn = 1.f / sqrtf(sred[0] + 1e-12f);
  __syncthreads();
  const float rnv = srn;

  const int wv = t >> 6, lane = t & 63;
  float zlv[8];
#pragma unroll
  for (int m = 0; m < 8; m++) zlv[m] = zs[lane * 8 + m];

  const float* cbase = en + (size_t)c * 524288;
  unsigned long long k1 = 0ULL; float d2 = 1e30f;
  for (int j = 0; j < 256; j++) {
    int k = (j << 2) | wv;                 // wave wv: k == wv (mod 4), asc
    const float* cr = cbase + (size_t)k * 512 + lane * 8;
    float4 c0 = *(const float4*)cr, c1 = *(const float4*)(cr + 4);
    float dt = zlv[0] * c0.x + zlv[1] * c0.y + zlv[2] * c0.z + zlv[3] * c0.w
             + zlv[4] * c1.x + zlv[5] * c1.y + zlv[6] * c1.z + zlv[7] * c1.w;
#pragma unroll
    for (int off = 32; off; off >>= 1) dt += __shfl_xor(dt, off);
    float d = qdist(dt, rnv);
    unsigned long long key =
        ((unsigned long long)(~flip_bits(d)) << 32) | (unsigned)(~k);
    if (key > k1) { d2 = fminf(d2, (k1 == 0ULL) ? 1e30f : dist_of_key(k1)); k1 = key; }
    else d2 = fminf(d2, d);
  }
  if (lane == 0) { wk[wv] = k1; wd2[wv] = d2; }
  __syncthreads();
  if (t == 0) {
    unsigned long long kb = wk[0]; float s2 = wd2[0];
#pragma unroll
    for (int w = 1; w < 4; w++) {
      unsigned long long q = wk[w]; float qd2 = wd2[w];
      if (q > kb) { s2 = fminf(qd2, dist_of_key(kb)); kb = q; }
      else s2 = fminf(s2, dist_of_key(q));
    }
    int code = (int)(~(unsigned)kb);
    float d1 = dist_of_key(kb);
    out[CODES_OFF + (unsigned long long)n * 3 + c] = (float)code;
    fcode = code;
    if (s2 - d1 < TAU_DIST) {            // exact near-tie: fp64 rescue
      int slot = atomicAdd(fc2, 1);
      if (slot < MAXF) { flags2[2 * slot] = n; flags2[2 * slot + 1] = c; }
    }
  }
  __syncthreads();
  const int fk = fcode;
  if (t < 128) {
    const float* er = en + ((size_t)c * 1024 + fk) * 512;
    float4 v = ((const float4*)er)[t];
    *(float4*)(out + TOKEMB_OFF + (unsigned long long)n * 1536 + c * 512 + t * 4) = v;
  }
}

// ---------------------------------------------------------------------------
// Tier 2: fp64 rescue — recompute flagged (row, codebook) from h0 in double,
// apply the reference's fp32 quantization, argmin with lowest-index tie-break.
__global__ __launch_bounds__(256)
void rescue_fp64(const float* __restrict__ h0,
                 const float* __restrict__ W1, const float* __restrict__ b1,
                 const float* __restrict__ W2, const float* __restrict__ b2,
                 const float* __restrict__ Wm, const float* __restrict__ bm,
                 const float* __restrict__ Wt, const float* __restrict__ bt,
                 const float* __restrict__ Wp, const float* __restrict__ bp,
                 const float* __restrict__ cbm, const float* __restrict__ cbt,
                 const float* __restrict__ cbp,
                 const float* __restrict__ en,
                 const int* __restrict__ flag_cnt, const int* __restrict__ flags,
                 float* __restrict__ out)
{
  int nf = *flag_cnt; if (nf > MAXF) nf = MAXF;
  const int b = blockIdx.x;
  if (b >= nf) return;
  const int n = flags[2 * b];
  const int c = flags[2 * b + 1];
  const int t = threadIdx.x;

  __shared__ double s1[512];
  __shared__ double s2[512];
  __shared__ double sred[256];
  __shared__ float sd4[4];
  __shared__ int sk4[4];
  __shared__ double shz;

  const float* Wc = (c == 0) ? Wm : (c == 1) ? Wt : Wp;
  const float* bc = (c == 0) ? bm : (c == 1) ? bt : bp;
  const float* cb = (c == 0) ? cbm : (c == 1) ? cbt : cbp;
  const float* h0r = h0 + (size_t)n * 1024;

  { // h1 = relu(h0 @ W1 + b1)
    double a0 = 0.0, a1 = 0.0;
    for (int i = 0; i < 1024; i++) {
      double h = (double)h0r[i];
      a0 = fma(h, (double)W1[(size_t)i * 512 + t], a0);
      a1 = fma(h, (double)W1[(size_t)i * 512 + t + 256], a1);
    }
    s1[t]       = fmax(a0 + (double)b1[t], 0.0);
    s1[t + 256] = fmax(a1 + (double)b1[t + 256], 0.0);
  }
  __syncthreads();
  { // H = relu(h1 @ W2 + b2)
    double a0 = 0.0, a1 = 0.0;
    for (int i = 0; i < 512; i++) {
      double h = s1[i];
      a0 = fma(h, (double)W2[(size_t)i * 512 + t], a0);
      a1 = fma(h, (double)W2[(size_t)i * 512 + t + 256], a1);
    }
    s2[t]       = fmax(a0 + (double)b2[t], 0.0);
    s2[t + 256] = fmax(a1 + (double)b2[t + 256], 0.0);
  }
  __syncthreads();
  { // z = H @ Wc + bc
    double a0 = 0.0, a1 = 0.0;
    for (int i = 0; i < 512; i++) {
      double h = s2[i];
      a0 = fma(h, (double)Wc[(size_t)i * 512 + t], a0);
      a1 = fma(h, (double)Wc[(size_t)i * 512 + t + 256], a1);
    }
    __syncthreads();
    s1[t]       = a0 + (double)bc[t];
    s1[t + 256] = a1 + (double)bc[t + 256];
  }
  __syncthreads();
  sred[t] = s1[t] * s1[t] + s1[t + 256] * s1[t + 256];
  __syncthreads();
  for (int s = 128; s > 0; s >>= 1) {
    if (t < s) sred[t] += sred[t + s];
    __syncthreads();
  }
  if (t == 0) shz = 1.0 / sqrt(sred[0] + 1e-12);
  __syncthreads();
  const double rz = shz;

  const int wv = t >> 6, lane = t & 63;
  double zl[8];
#pragma unroll
  for (int m = 0; m < 8; m++) zl[m] = s1[lane * 8 + m];
  float bd = 1e30f; int bkk = 1 << 30;
  for (int j = 0; j < 256; j++) {
    int k = (j << 2) | wv;
    const float* cr = cb + (size_t)k * 512 + lane * 8;
    float4 c0 = *(const float4*)cr, c1 = *(const float4*)(cr + 4);
    double x0 = c0.x, x1 = c0.y, x2 = c0.z, x3 = c0.w;
    double x4 = c1.x, x5 = c1.y, x6 = c1.z, x7 = c1.w;
    double dt = zl[0]*x0 + zl[1]*x1 + zl[2]*x2 + zl[3]*x3
              + zl[4]*x4 + zl[5]*x5 + zl[6]*x6 + zl[7]*x7;
    double nc = x0*x0 + x1*x1 + x2*x2 + x3*x3 + x4*x4 + x5*x5 + x6*x6 + x7*x7;
#pragma unroll
    for (int off = 32; off; off >>= 1) {
      dt += __shfl_xor(dt, off);
      nc += __shfl_xor(nc, off);
    }
    double sim64 = dt * rz * (1.0 / sqrt(nc + 1e-12));
    float s32 = (float)sim64;
    float d32 = __fadd_rn(2.0f, -__fmul_rn(2.0f, s32));
    if (d32 < bd) { bd = d32; bkk = k; }
  }
  if (lane == 0) { sd4[wv] = bd; sk4[wv] = bkk; }
  __syncthreads();
  if (t == 0) {
    float d = sd4[0]; int k = sk4[0];
#pragma unroll
    for (int w = 1; w < 4; w++)
      if (sd4[w] < d || (sd4[w] == d && sk4[w] < k)) { d = sd4[w]; k = sk4[w]; }
    sk4[0] = k;
    out[CODES_OFF + (unsigned long long)n * 3 + c] = (float)k;
  }
  __syncthreads();
  const int fk = sk4[0];
  if (t < 128) {
    const float* er = en + ((size_t)c * 1024 + fk) * 512;
    float4 v = ((const float4*)er)[t];
    *(float4*)(out + TOKEMB_OFF + (unsigned long long)n * 1536 + c * 512 + t * 4) = v;
  }
}

// ---------------------------------------------------------------------------
// rn = 1/||z~|| from the hi/lo planes (z~ = hi + lo reconstructed).
__global__ __launch_bounds__(256)
void row_rnorm(const unsigned short* __restrict__ zh,
               const unsigned short* __restrict__ zl,
               float* __restrict__ rn)
{
  const int lane = threadIdx.x & 63;
  const long r = (long)blockIdx.x * 4 + (threadIdx.x >> 6);
  const int cc = (int)(r >> 15), n = (int)(r & 32767);
  const size_t base = (size_t)n * 1536 + (size_t)cc * 512 + lane * 8;
  uint4 h = *(const uint4*)(zh + base);
  uint4 lo = *(const uint4*)(zl + base);
  float s = 0.f;
  const unsigned hw[4] = {h.x, h.y, h.z, h.w};
  const unsigned lw[4] = {lo.x, lo.y, lo.z, lo.w};
#pragma unroll
  for (int i = 0; i < 4; i++) {
    float ze = __uint_as_float(hw[i] << 16) + __uint_as_float(lw[i] << 16);
    float zo = __uint_as_float(hw[i] & 0xFFFF0000u) + __uint_as_float(lw[i] & 0xFFFF0000u);
    s = fmaf(ze, ze, s);
    s = fmaf(zo, zo, s);
  }
#pragma unroll
  for (int off = 32; off; off >>= 1) s += __shfl_xor(s, off);
  if (lane == 0) rn[r] = 1.f / sqrtf(s + 1e-12f);
}

// normalize codebooks -> en (fp32) and pre-split bf16 hi/lo for the MFMA sim
__global__ __launch_bounds__(256)
void cb_norm(const float* __restrict__ cbm, const float* __restrict__ cbt,
             const float* __restrict__ cbp, float* __restrict__ en,
             unsigned short* __restrict__ en_hi, unsigned short* __restrict__ en_lo)
{
  const int lane = threadIdx.x & 63;
  const long r = (long)blockIdx.x * 4 + (threadIdx.x >> 6);
  const int cc = (int)(r >> 10), k = (int)(r & 1023);
  const float* cb = (cc == 0) ? cbm : (cc == 1) ? cbt : cbp;
  const float* p = cb + (long)k * 512 + lane * 8;
  float4 v0 = *(const float4*)p, v1 = *(const float4*)(p + 4);
  float s = v0.x * v0.x + v0.y * v0.y + v0.z * v0.z + v0.w * v0.w
          + v1.x * v1.x + v1.y * v1.y + v1.z * v1.z + v1.w * v1.w;
#pragma unroll
  for (int off = 32; off; off >>= 1) s += __shfl_xor(s, off);
  float sc = 1.f / sqrtf(s + 1e-12f);
  v0.x *= sc; v0.y *= sc; v0.z *= sc; v0.w *= sc;
  v1.x *= sc; v1.y *= sc; v1.z *= sc; v1.w *= sc;
  const size_t g = (size_t)cc * 524288 + (size_t)k * 512 + lane * 8;
  float* q = en + g;
  *(float4*)q = v0; *(float4*)(q + 4) = v1;
  unsigned h[8], lo[8];
  split2(v0.x, h[0], lo[0]); split2(v0.y, h[1], lo[1]);
  split2(v0.z, h[2], lo[2]); split2(v0.w, h[3], lo[3]);
  split2(v1.x, h[4], lo[4]); split2(v1.y, h[5], lo[5]);
  split2(v1.z, h[6], lo[6]); split2(v1.w, h[7], lo[7]);
  uint4 hp, lp;
  hp.x = h[0] | (h[1] << 16);  hp.y = h[2] | (h[3] << 16);
  hp.z = h[4] | (h[5] << 16);  hp.w = h[6] | (h[7] << 16);
  lp.x = lo[0] | (lo[1] << 16); lp.y = lo[2] | (lo[3] << 16);
  lp.z = lo[4] | (lo[5] << 16); lp.w = lo[6] | (lo[7] << 16);
  *(uint4*)(en_hi + g) = hp;
  *(uint4*)(en_lo + g) = lp;
}

__global__ __launch_bounds__(256)
void logits_alpha(const float* __restrict__ H, const float* __restrict__ Wk,
                  const float* __restrict__ bk, float* __restrict__ alpha)
{
  const int lane = threadIdx.x & 63;
  const long n = (long)blockIdx.x * 4 + (threadIdx.x >> 6);
  const float* p = H + n * 512 + lane * 8;
  const float* w = Wk + lane * 8;
  float4 a0 = *(const float4*)p, a1 = *(const float4*)(p + 4);
  float4 w0 = *(const float4*)w, w1 = *(const float4*)(w + 4);
  float s = a0.x * w0.x + a0.y * w0.y + a0.z * w0.z + a0.w * w0.w
          + a1.x * w1.x + a1.y * w1.y + a1.z * w1.z + a1.w * w1.w;
#pragma unroll
  for (int off = 32; off; off >>= 1) s += __shfl_xor(s, off);
  if (lane == 0) alpha[n] = 1.f / (1.f + expf(-(s + bk[0])));
}

// top-32 by alpha with index tie-break; keys cached in registers (one global
// read per element instead of 32).
__global__ __launch_bounds__(1024)
void topk32(const float* __restrict__ alpha, float* __restrict__ out)
{
  __shared__ unsigned long long sk[1024];
  const int tid = threadIdx.x;
  unsigned long long key[32];
#pragma unroll
  for (int j = 0; j < 32; j++) {
    int i = tid + j * 1024;
    key[j] = ((unsigned long long)flip_bits(alpha[i]) << 32) | (unsigned)(~i);
  }
  unsigned long long prev = ~0ULL;
  for (int it = 0; it < 32; it++) {
    unsigned long long best = 0;
#pragma unroll
    for (int j = 0; j < 32; j++)
      if (key[j] < prev && key[j] > best) best = key[j];
    sk[tid] = best;
    __syncthreads();
    for (int s = 512; s > 0; s >>= 1) {
      if (tid < s) { unsigned long long q = sk[tid + s]; if (q > sk[tid]) sk[tid] = q; }
      __syncthreads();
    }
    unsigned long long sel = sk[0];
    __syncthreads();
    if (tid == 0) out[it] = (float)(~(unsigned)sel);
    prev = sel;
  }
}

extern "C" void kernel_launch(void* const* d_in, const int* in_sizes, int n_in,
                              void* d_out, int out_size, void* d_ws, size_t ws_size,
                              hipStream_t stream)
{
  (void)in_sizes; (void)n_in; (void)out_size; (void)ws_size;
  const float* h0  = (const float*)d_in[0];
  const float* W1  = (const float*)d_in[1];
  const float* b1  = (const float*)d_in[2];
  const float* W2  = (const float*)d_in[3];
  const float* b2  = (const float*)d_in[4];
  const float* Wm  = (const float*)d_in[5];
  const float* bm  = (const float*)d_in[6];
  const float* Wt  = (const float*)d_in[7];
  const float* bt  = (const float*)d_in[8];
  const float* Wp  = (const float*)d_in[9];
  const float* bp  = (const float*)d_in[10];
  const float* cbm = (const float*)d_in[11];
  const float* cbt = (const float*)d_in[12];
  const float* cbp = (const float*)d_in[13];
  const float* Wk  = (const float*)d_in[14];
  const float* bk  = (const float*)d_in[15];
  float* out = (float*)d_out;
  float* ws  = (float*)d_ws;

  // late-phase planes
  unsigned short* zh = (unsigned short*)ws;                 // [32768][1536]
  unsigned short* zl = (unsigned short*)ws + 50331648ULL;   // [32768][1536]
  // early-phase overlays inside the z region (dead before planes written)
  float* h1 = ws;                                           // [32768,512] f32
  unsigned short* W1h = (unsigned short*)ws + 33554432ULL;  // byte 64MB, 1MB
  unsigned short* W1l = W1h + 524288ULL;
  unsigned short* W2h = W1l + 524288ULL;                    // 0.5MB
  unsigned short* W2l = W2h + 262144ULL;
  // persistent region
  float* en = ws + 50331648ULL;      // [3,1024,512] f32
  float* rn = ws + 51904512ULL;      // [3*32768]
  float* al = ws + 52002816ULL;      // [32768]
  int* fc1    = (int*)(ws + 52035584ULL);
  int* fc2    = fc1 + 1;
  int* flags1 = fc1 + 2;                             // [MAXF1][2]
  int* flags2 = flags1 + 2 * MAXF1;                  // [MAXF][2]
  unsigned short* en_hi = (unsigned short*)(ws + 52068356ULL);  // [3*1024*512]
  unsigned short* en_lo = (unsigned short*)(ws + 52854788ULL);  // [3*1024*512]
  unsigned short* Wh = (unsigned short*)(ws + 53641220ULL);     // [3][512][512]
  unsigned short* Wl = (unsigned short*)(ws + 54034436ULL);     // [3][512][512]
  float* H  = out;
  float* lvq = out + LVQ_OFF;

  hipMemsetAsync(lvq, 0, sizeof(float), stream);
  hipMemsetAsync(fc1, 0, 2 * sizeof(int), stream);

  // all weight pre-splits in one launch
  wsplit_all<<<768, 256, 0, stream>>>(W1, W2, Wm, Wt, Wp,
                                      W1h, W1l, W2h, W2l, Wh, Wl);

  // encoder on MFMA: h1 = relu(h0@W1+b1), H = relu(h1@W2+b2)
  mfma_gemm128<1, 0><<<dim3(256, 4), 256, 0, stream>>>(
      h0, 1024, 1024, W1h, W1l, b1, h1, 512, nullptr, nullptr, 0, 0);
  mfma_gemm128<1, 0><<<dim3(256, 4), 256, 0, stream>>>(
      h1, 512, 512, W2h, W2l, b2, H, 512, nullptr, nullptr, 0, 0);

  // z projections on MFMA, written directly as bf16 hi/lo planes
  mfma_gemm128<0, 1><<<dim3(256, 4), 256, 0, stream>>>(
      H, 512, 512, Wh + 0 * 262144, Wl + 0 * 262144, bm, nullptr, 0,
      zh, zl, 1536, 0);
  mfma_gemm128<0, 1><<<dim3(256, 4), 256, 0, stream>>>(
      H, 512, 512, Wh + 1 * 262144, Wl + 1 * 262144, bt, nullptr, 0,
      zh, zl, 1536, 512);
  mfma_gemm128<0, 1><<<dim3(256, 4), 256, 0, stream>>>(
      H, 512, 512, Wh + 2 * 262144, Wl + 2 * 262144, bp, nullptr, 0,
      zh, zl, 1536, 1024);

  row_rnorm<<<24576, 256, 0, stream>>>(zh, zl, rn);
  cb_norm<<<768, 256, 0, stream>>>(cbm, cbt, cbp, en, en_hi, en_lo);
  sim_argmax<<<dim3(256, 3), 256, 0, stream>>>(zh, zl, en, en_hi, en_lo, rn, out, lvq,
                                               fc1, flags1);
  refine_fp32<<<MAXF1, 256, 0, stream>>>(H, Wm, bm, Wt, bt, Wp, bp, en,
                                         fc1, flags1, fc2, flags2, out);
  rescue_fp64<<<MAXF, 256, 0, stream>>>(h0, W1, b1, W2, b2, Wm, bm, Wt, bt, Wp, bp,
                                        cbm, cbt, cbp, en, fc2, flags2, out);
  logits_alpha<<<8192, 256, 0, stream>>>(H, Wk, bk, al);
  topk32<<<1, 1024, 0, stream>>>(al, out + KEYIDX_OFF);
}